// Round 1
// baseline (2617.696 us; speedup 1.0000x reference)
//
#include <hip/hip_runtime.h>
#include <hip/hip_bf16.h>
#include <math.h>

// Sizes (fixed by the problem)
#define B 64
#define T 64
#define E_ENC 1024
#define EMB 512
#define D 512
#define L 32
#define S 31
#define A 512
#define V 30000
#define KSZ 7

// ---------------------------------------------------------------------------
// wv[e] = sum_a Wp[a]*Wenc[a,e];  c0 = sum_a benc[a]*Wp[a]
__global__ void k_wv(const float* __restrict__ Wenc, const float* __restrict__ Wp,
                     const float* __restrict__ benc, float* __restrict__ wv,
                     float* __restrict__ c0) {
  __shared__ float red[256];
  int e = blockIdx.x * 256 + threadIdx.x;   // grid 4 x 256 covers 1024
  float s = 0.f;
  for (int a = 0; a < A; ++a) s += Wp[a] * Wenc[(size_t)a * E_ENC + e];
  wv[e] = s;
  if (blockIdx.x == 0) {
    int t = threadIdx.x;
    float v = Wp[t] * benc[t] + Wp[t + 256] * benc[t + 256];
    red[t] = v;
    __syncthreads();
    for (int off = 128; off > 0; off >>= 1) {
      if (t < off) red[t] += red[t + off];
      __syncthreads();
    }
    if (t == 0) c0[0] = red[0];
  }
}

// ---------------------------------------------------------------------------
// Per-b: enc_mean[b,:], fscore -> softmax over t -> ctx[b,:]
__global__ void k_mean_ctx(const float* __restrict__ features, const float* __restrict__ wv,
                           const float* __restrict__ c0, float* __restrict__ enc_mean,
                           float* __restrict__ ctx) {
  int b = blockIdx.x, tid = threadIdx.x;
  const float* fb = features + (size_t)b * T * E_ENC;
  __shared__ float s_attw[T];

  // mean over t (each thread 4 columns)
  float m0 = 0, m1 = 0, m2 = 0, m3 = 0;
  for (int t = 0; t < T; ++t) {
    const float* r = fb + t * E_ENC;
    m0 += r[tid]; m1 += r[tid + 256]; m2 += r[tid + 512]; m3 += r[tid + 768];
  }
  size_t eb = (size_t)b * E_ENC;
  enc_mean[eb + tid]       = m0 * (1.f / 64.f);
  enc_mean[eb + tid + 256] = m1 * (1.f / 64.f);
  enc_mean[eb + tid + 512] = m2 * (1.f / 64.f);
  enc_mean[eb + tid + 768] = m3 * (1.f / 64.f);

  // fscore[t] = c0 + features[b,t,:].wv  (4 threads per t)
  {
    int t = tid >> 2, part = tid & 3;
    const float* r = fb + t * E_ENC + part * 256;
    const float* wp = wv + part * 256;
    float s = 0.f;
    for (int e = 0; e < 256; e += 4) {
      float4 f4 = *(const float4*)(r + e);
      float4 w4 = *(const float4*)(wp + e);
      s += f4.x * w4.x + f4.y * w4.y + f4.z * w4.z + f4.w * w4.w;
    }
    s += __shfl_xor(s, 1);
    s += __shfl_xor(s, 2);
    if (part == 0) s_attw[t] = s + c0[0];
  }
  __syncthreads();
  // softmax over the 64 values in wave 0
  if (tid < 64) {
    float v = s_attw[tid];
    float mx = v;
    #pragma unroll
    for (int off = 32; off > 0; off >>= 1) mx = fmaxf(mx, __shfl_xor(mx, off));
    float e = expf(v - mx);
    float sm = e;
    #pragma unroll
    for (int off = 32; off > 0; off >>= 1) sm += __shfl_xor(sm, off);
    s_attw[tid] = e / sm;
  }
  __syncthreads();
  // ctx[b,:] = sum_t attw[t] * features[b,t,:]
  float ca = 0, cb = 0, cc = 0, cd = 0;
  for (int t = 0; t < T; ++t) {
    float w = s_attw[t];
    const float* r = fb + t * E_ENC;
    ca += w * r[tid]; cb += w * r[tid + 256]; cc += w * r[tid + 512]; cd += w * r[tid + 768];
  }
  ctx[eb + tid]       = ca;
  ctx[eb + tid + 256] = cb;
  ctx[eb + tid + 512] = cc;
  ctx[eb + tid + 768] = cd;
}

// ---------------------------------------------------------------------------
// base1[b,d] = b1[d] + enc_mean[b,:1024] . W1[d,:1024]
__global__ void k_base1(const float* __restrict__ enc_mean, const float* __restrict__ W1,
                        const float* __restrict__ b1, float* __restrict__ base1) {
  __shared__ float em[E_ENC];
  int b = blockIdx.x, tid = threadIdx.x;
  for (int i = tid; i < E_ENC; i += 256) em[i] = enc_mean[(size_t)b * E_ENC + i];
  __syncthreads();
  for (int d = tid; d < D; d += 256) {
    const float* w = W1 + (size_t)d * (E_ENC + EMB);
    float acc = 0.f;
    for (int e = 0; e < E_ENC; e += 4) {
      float4 w4 = *(const float4*)(w + e);
      acc += w4.x * em[e] + w4.y * em[e + 1] + w4.z * em[e + 2] + w4.w * em[e + 3];
    }
    base1[b * D + d] = acc + b1[d];
  }
}

// ---------------------------------------------------------------------------
// x1[b,l,d] = base1[b,d] + emb[captions[b,l],:] . W1[d,1024:1536]
__global__ void k_x1(const float* __restrict__ embed_W, const int* __restrict__ captions,
                     const float* __restrict__ W1, const float* __restrict__ base1,
                     float* __restrict__ x1) {
  __shared__ float emb[L][EMB];  // exactly 64 KiB
  int b = blockIdx.x, tid = threadIdx.x;
  for (int i = tid; i < L * EMB; i += 256) {
    int l = i >> 9, c = i & 511;
    emb[l][c] = embed_W[(size_t)captions[b * L + l] * EMB + c];
  }
  __syncthreads();
  for (int d = tid; d < D; d += 256) {
    const float* wrow = W1 + (size_t)d * (E_ENC + EMB) + E_ENC;
    float acc[L];
    #pragma unroll
    for (int l = 0; l < L; ++l) acc[l] = 0.f;
    for (int e = 0; e < EMB; ++e) {
      float we = wrow[e];
      #pragma unroll
      for (int l = 0; l < L; ++l) acc[l] += we * emb[l][e];
    }
    float bb = base1[b * D + d];
    #pragma unroll
    for (int l = 0; l < L; ++l) x1[((size_t)b * L + l) * D + d] = acc[l] + bb;
  }
}

// ---------------------------------------------------------------------------
// Causal conv (K=7) + GLU gate + residual.  x layout [B,L,D].
// Block: 512 threads. grid (B, 2 lh, 2 dg). Threads 0..255: y_a for 256
// channels; 256..511: y_b for the same channels. Combine via LDS.
template <int LH>
__device__ __forceinline__ void conv_body(const float* __restrict__ xin,
                                          const float* __restrict__ w,
                                          const float* __restrict__ bias,
                                          float* __restrict__ xout, int b, int dg, int tid,
                                          float xs[22][512], float sb[256][17]) {
  constexpr int ROW_LO = LH ? 10 : 0;
  constexpr int NROWS  = LH ? 22 : 16;
  constexpr int L0     = LH ? 16 : 0;
  const float* xb = xin + (size_t)b * L * D;
  for (int i = tid; i < NROWS * 512; i += 512) {
    int r = i >> 9, c = i & 511;
    xs[r][c] = xb[(ROW_LO + r) * D + c];
  }
  __syncthreads();
  int half = tid >> 8;        // 0 = gate numerator channel, 1 = sigmoid channel
  int p = tid & 255;
  int d = dg * 256 + p;       // 0..511
  int c = d + half * D;       // conv out channel 0..1023
  float acc[16];
  float bi = bias[c];
  #pragma unroll
  for (int l = 0; l < 16; ++l) acc[l] = bi;
  const float* wr = w + (size_t)c * (D * KSZ);
  for (int dp = 0; dp < D; ++dp) {
    float wk[KSZ];
    #pragma unroll
    for (int k = 0; k < KSZ; ++k) wk[k] = wr[dp * KSZ + k];
    #pragma unroll
    for (int jj = 0; jj < NROWS; ++jj) {
      float xv = xs[jj][dp];
      #pragma unroll
      for (int k = 0; k < KSZ; ++k) {
        int l = jj + ROW_LO + 6 - k;       // compile-time per (jj,k)
        if (l >= L0 && l < L0 + 16) acc[l - L0] += xv * wk[k];
      }
    }
  }
  if (half) {
    #pragma unroll
    for (int l = 0; l < 16; ++l) sb[p][l] = acc[l];
  }
  __syncthreads();
  if (!half) {
    #pragma unroll
    for (int li = 0; li < 16; ++li) {
      float yb = sb[p][li];
      float g = acc[li] / (1.f + expf(-yb));   // y_a * sigmoid(y_b)
      int l = L0 + li;
      float res = xs[l - ROW_LO][d];
      xout[((size_t)b * L + l) * D + d] = g + res;
    }
  }
}

__global__ __launch_bounds__(512) void k_conv(const float* __restrict__ xin,
                                              const float* __restrict__ w,
                                              const float* __restrict__ bias,
                                              float* __restrict__ xout) {
  __shared__ float xs[22][512];
  __shared__ float sb[256][17];
  int b = blockIdx.x, lh = blockIdx.y, dg = blockIdx.z, tid = threadIdx.x;
  if (lh == 0) conv_body<0>(xin, w, bias, xout, b, dg, tid, xs, sb);
  else         conv_body<1>(xin, w, bias, xout, b, dg, tid, xs, sb);
}

// ---------------------------------------------------------------------------
// cbase[b,v] = b2[v] + ctx[b,:1024] . W2[v,:1024]
// grid (118, 2): blockIdx.x -> 256 v's, blockIdx.y -> 32 b's
__global__ void k_cbase(const float* __restrict__ ctx, const float* __restrict__ W2,
                        const float* __restrict__ b2, float* __restrict__ cbase) {
  __shared__ float sc[32][256];
  int v = blockIdx.x * 256 + threadIdx.x;
  int b0 = blockIdx.y * 32;
  bool vok = v < V;
  int vc = vok ? v : V - 1;
  float acc[32];
  #pragma unroll
  for (int bb = 0; bb < 32; ++bb) acc[bb] = 0.f;
  for (int et = 0; et < 4; ++et) {
    __syncthreads();
    for (int i = threadIdx.x; i < 32 * 256; i += 256) {
      int bb = i >> 8;   // iter
      int e = i & 255;   // == threadIdx.x
      sc[bb][e] = ctx[(size_t)(b0 + bb) * E_ENC + et * 256 + e];
    }
    __syncthreads();
    const float* wrow = W2 + (size_t)vc * (E_ENC + D) + et * 256;
    for (int e = 0; e < 256; e += 4) {
      float4 w4 = *(const float4*)(wrow + e);
      #pragma unroll
      for (int bb = 0; bb < 32; ++bb)
        acc[bb] += w4.x * sc[bb][e] + w4.y * sc[bb][e + 1] + w4.z * sc[bb][e + 2] + w4.w * sc[bb][e + 3];
    }
  }
  if (vok) {
    float bias = b2[v];
    #pragma unroll
    for (int bb = 0; bb < 32; ++bb) cbase[(size_t)(b0 + bb) * V + v] = acc[bb] + bias;
  }
}

// ---------------------------------------------------------------------------
// logits[b,s,v] = cbase[b,v] + x3[b,s,:] . W2[v,1024:1536]   (s = l < 31)
// fp32 tiled GEMM: M=2048 (b*32+l), N=30000, K=512. 128x128 tile, 8x8/thread.
__global__ __launch_bounds__(256) void k_logits(const float* __restrict__ x3,
                                                const float* __restrict__ W2,
                                                const float* __restrict__ cbase,
                                                float* __restrict__ out) {
  __shared__ float As[32][129];   // [k][row]
  __shared__ float Bs[32][129];   // [k][v]
  int v0 = blockIdx.x * 128;
  int g0 = blockIdx.y * 128;
  int tid = threadIdx.x;
  int tx = tid & 15, ty = tid >> 4;
  float acc[8][8];
  #pragma unroll
  for (int i = 0; i < 8; ++i)
    #pragma unroll
    for (int j = 0; j < 8; ++j) acc[i][j] = 0.f;

  for (int kt = 0; kt < 16; ++kt) {
    {
      int r = tid >> 5, kk = tid & 31;
      #pragma unroll
      for (int p = 0; p < 16; ++p, r += 8) {
        As[kk][r] = x3[(size_t)(g0 + r) * D + kt * 32 + kk];
        int vv = v0 + r; if (vv > V - 1) vv = V - 1;
        Bs[kk][r] = W2[(size_t)vv * (E_ENC + D) + E_ENC + kt * 32 + kk];
      }
    }
    __syncthreads();
    #pragma unroll
    for (int k = 0; k < 32; ++k) {
      float a[8], bv[8];
      #pragma unroll
      for (int i = 0; i < 8; ++i) a[i] = As[k][ty + 16 * i];
      #pragma unroll
      for (int j = 0; j < 8; ++j) bv[j] = Bs[k][tx + 16 * j];
      #pragma unroll
      for (int i = 0; i < 8; ++i)
        #pragma unroll
        for (int j = 0; j < 8; ++j) acc[i][j] += a[i] * bv[j];
    }
    __syncthreads();
  }

  #pragma unroll
  for (int i = 0; i < 8; ++i) {
    int g = g0 + ty + 16 * i;
    int b = g >> 5, l = g & 31;
    if (l >= S) continue;
    size_t orow = ((size_t)b * S + l) * V;
    size_t crow = (size_t)b * V;
    #pragma unroll
    for (int j = 0; j < 8; ++j) {
      int v = v0 + tx + 16 * j;
      if (v < V) out[orow + v] = acc[i][j] + cbase[crow + v];
    }
  }
}

// ---------------------------------------------------------------------------
extern "C" void kernel_launch(void* const* d_in, const int* in_sizes, int n_in,
                              void* d_out, int out_size, void* d_ws, size_t ws_size,
                              hipStream_t stream) {
  const float* features = (const float*)d_in[0];
  const int*   captions = (const int*)d_in[1];
  // d_in[2] lengths: unused by the reference
  const float* embed_W  = (const float*)d_in[3];
  const float* W1   = (const float*)d_in[4];
  const float* b1   = (const float*)d_in[5];
  const float* cw1  = (const float*)d_in[6];
  const float* cb1  = (const float*)d_in[7];
  const float* cw2  = (const float*)d_in[8];
  const float* cb2  = (const float*)d_in[9];
  const float* Wenc = (const float*)d_in[10];
  const float* benc = (const float*)d_in[11];
  // Wdec (12), bdec (13), bp (15): cancel in softmax -> unused
  const float* Wp   = (const float*)d_in[14];
  const float* W2   = (const float*)d_in[16];
  const float* b2   = (const float*)d_in[17];
  float* out = (float*)d_out;

  float* ws = (float*)d_ws;
  float* wv       = ws;               // 1024
  float* c0       = ws + 1024;        // 16
  float* enc_mean = ws + 1040;        // 65536
  float* ctx      = ws + 66576;       // 65536
  float* base1    = ws + 132112;      // 32768
  float* xA       = ws + 164880;      // 1048576  (x1, then x3)
  float* xB       = ws + 1213456;     // 1048576  (x2)
  float* cbase    = ws + 2262032;     // 1920000
  // total: 4,182,032 floats = 16.7 MB

  hipLaunchKernelGGL(k_wv,       dim3(4),         dim3(256), 0, stream, Wenc, Wp, benc, wv, c0);
  hipLaunchKernelGGL(k_mean_ctx, dim3(B),         dim3(256), 0, stream, features, wv, c0, enc_mean, ctx);
  hipLaunchKernelGGL(k_base1,    dim3(B),         dim3(256), 0, stream, enc_mean, W1, b1, base1);
  hipLaunchKernelGGL(k_x1,       dim3(B),         dim3(256), 0, stream, embed_W, captions, W1, base1, xA);
  hipLaunchKernelGGL(k_conv,     dim3(B, 2, 2),   dim3(512), 0, stream, xA, cw1, cb1, xB);
  hipLaunchKernelGGL(k_conv,     dim3(B, 2, 2),   dim3(512), 0, stream, xB, cw2, cb2, xA);
  hipLaunchKernelGGL(k_cbase,    dim3(118, 2),    dim3(256), 0, stream, ctx, W2, b2, cbase);
  hipLaunchKernelGGL(k_logits,   dim3(235, 16),   dim3(256), 0, stream, xA, W2, cbase, out);
}

// Round 2
// 1469.408 us; speedup vs baseline: 1.7815x; 1.7815x over previous
//
#include <hip/hip_runtime.h>
#include <hip/hip_bf16.h>
#include <math.h>

// Sizes (fixed by the problem)
#define B 64
#define T 64
#define E_ENC 1024
#define EMB 512
#define D 512
#define L 32
#define S 31
#define A 512
#define V 30000
#define KSZ 7

typedef __attribute__((ext_vector_type(8))) short bf16x8;
typedef __attribute__((ext_vector_type(4))) float f32x4;

__device__ __forceinline__ unsigned short f2bf(float f) {
  union { float f; unsigned int u; } x; x.f = f;
  unsigned int r = (x.u + 0x7fffu + ((x.u >> 16) & 1u)) >> 16;
  return (unsigned short)r;
}

__device__ __forceinline__ void gload_lds16(const void* g, void* l) {
  __builtin_amdgcn_global_load_lds(
      (const __attribute__((address_space(1))) unsigned int*)g,
      (__attribute__((address_space(3))) unsigned int*)l, 16, 0, 0);
}

// ---------------------------------------------------------------------------
// wv[e] = sum_a Wp[a]*Wenc[a,e];  c0 = sum_a benc[a]*Wp[a]
__global__ void k_wv(const float* __restrict__ Wenc, const float* __restrict__ Wp,
                     const float* __restrict__ benc, float* __restrict__ wv,
                     float* __restrict__ c0) {
  __shared__ float red[256];
  int e = blockIdx.x * 256 + threadIdx.x;   // grid 4 x 256 covers 1024
  float s = 0.f;
  for (int a = 0; a < A; ++a) s += Wp[a] * Wenc[(size_t)a * E_ENC + e];
  wv[e] = s;
  if (blockIdx.x == 0) {
    int t = threadIdx.x;
    float v = Wp[t] * benc[t] + Wp[t + 256] * benc[t + 256];
    red[t] = v;
    __syncthreads();
    for (int off = 128; off > 0; off >>= 1) {
      if (t < off) red[t] += red[t + off];
      __syncthreads();
    }
    if (t == 0) c0[0] = red[0];
  }
}

// ---------------------------------------------------------------------------
// Per-b: enc_mean[b,:], fscore -> softmax over t -> ctx[b,:]
__global__ void k_mean_ctx(const float* __restrict__ features, const float* __restrict__ wv,
                           const float* __restrict__ c0, float* __restrict__ enc_mean,
                           float* __restrict__ ctx) {
  int b = blockIdx.x, tid = threadIdx.x;
  const float* fb = features + (size_t)b * T * E_ENC;
  __shared__ float s_attw[T];

  float m0 = 0, m1 = 0, m2 = 0, m3 = 0;
  for (int t = 0; t < T; ++t) {
    const float* r = fb + t * E_ENC;
    m0 += r[tid]; m1 += r[tid + 256]; m2 += r[tid + 512]; m3 += r[tid + 768];
  }
  size_t eb = (size_t)b * E_ENC;
  enc_mean[eb + tid]       = m0 * (1.f / 64.f);
  enc_mean[eb + tid + 256] = m1 * (1.f / 64.f);
  enc_mean[eb + tid + 512] = m2 * (1.f / 64.f);
  enc_mean[eb + tid + 768] = m3 * (1.f / 64.f);

  {
    int t = tid >> 2, part = tid & 3;
    const float* r = fb + t * E_ENC + part * 256;
    const float* wp = wv + part * 256;
    float s = 0.f;
    for (int e = 0; e < 256; e += 4) {
      float4 f4 = *(const float4*)(r + e);
      float4 w4 = *(const float4*)(wp + e);
      s += f4.x * w4.x + f4.y * w4.y + f4.z * w4.z + f4.w * w4.w;
    }
    s += __shfl_xor(s, 1);
    s += __shfl_xor(s, 2);
    if (part == 0) s_attw[t] = s + c0[0];
  }
  __syncthreads();
  if (tid < 64) {
    float v = s_attw[tid];
    float mx = v;
    #pragma unroll
    for (int off = 32; off > 0; off >>= 1) mx = fmaxf(mx, __shfl_xor(mx, off));
    float e = expf(v - mx);
    float sm = e;
    #pragma unroll
    for (int off = 32; off > 0; off >>= 1) sm += __shfl_xor(sm, off);
    s_attw[tid] = e / sm;
  }
  __syncthreads();
  float ca = 0, cb = 0, cc = 0, cd = 0;
  for (int t = 0; t < T; ++t) {
    float w = s_attw[t];
    const float* r = fb + t * E_ENC;
    ca += w * r[tid]; cb += w * r[tid + 256]; cc += w * r[tid + 512]; cd += w * r[tid + 768];
  }
  ctx[eb + tid]       = ca;
  ctx[eb + tid + 256] = cb;
  ctx[eb + tid + 512] = cc;
  ctx[eb + tid + 768] = cd;
}

// ---------------------------------------------------------------------------
// base1[b,d] = b1[d] + enc_mean[b,:1024] . W1[d,:1024]
__global__ void k_base1(const float* __restrict__ enc_mean, const float* __restrict__ W1,
                        const float* __restrict__ b1, float* __restrict__ base1) {
  __shared__ float em[E_ENC];
  int b = blockIdx.x, tid = threadIdx.x;
  for (int i = tid; i < E_ENC; i += 256) em[i] = enc_mean[(size_t)b * E_ENC + i];
  __syncthreads();
  for (int d = tid; d < D; d += 256) {
    const float* w = W1 + (size_t)d * (E_ENC + EMB);
    float acc = 0.f;
    for (int e = 0; e < E_ENC; e += 4) {
      float4 w4 = *(const float4*)(w + e);
      acc += w4.x * em[e] + w4.y * em[e + 1] + w4.z * em[e + 2] + w4.w * em[e + 3];
    }
    base1[b * D + d] = acc + b1[d];
  }
}

// ---------------------------------------------------------------------------
// x1[b,l,d] = base1[b,d] + emb[captions[b,l],:] . W1[d,1024:1536]
__global__ void k_x1(const float* __restrict__ embed_W, const int* __restrict__ captions,
                     const float* __restrict__ W1, const float* __restrict__ base1,
                     float* __restrict__ x1) {
  __shared__ float emb[L][EMB];  // exactly 64 KiB
  int b = blockIdx.x, tid = threadIdx.x;
  for (int i = tid; i < L * EMB; i += 256) {
    int l = i >> 9, c = i & 511;
    emb[l][c] = embed_W[(size_t)captions[b * L + l] * EMB + c];
  }
  __syncthreads();
  for (int d = tid; d < D; d += 256) {
    const float* wrow = W1 + (size_t)d * (E_ENC + EMB) + E_ENC;
    float acc[L];
    #pragma unroll
    for (int l = 0; l < L; ++l) acc[l] = 0.f;
    for (int e = 0; e < EMB; ++e) {
      float we = wrow[e];
      #pragma unroll
      for (int l = 0; l < L; ++l) acc[l] += we * emb[l][e];
    }
    float bb = base1[b * D + d];
    #pragma unroll
    for (int l = 0; l < L; ++l) x1[((size_t)b * L + l) * D + d] = acc[l] + bb;
  }
}

// ---------------------------------------------------------------------------
// Causal conv (K=7) + GLU gate + residual.  x layout [B,L,D].
template <int LH>
__device__ __forceinline__ void conv_body(const float* __restrict__ xin,
                                          const float* __restrict__ w,
                                          const float* __restrict__ bias,
                                          float* __restrict__ xout, int b, int dg, int tid,
                                          float xs[22][512], float sb[256][17]) {
  constexpr int ROW_LO = LH ? 10 : 0;
  constexpr int NROWS  = LH ? 22 : 16;
  constexpr int L0     = LH ? 16 : 0;
  const float* xb = xin + (size_t)b * L * D;
  for (int i = tid; i < NROWS * 512; i += 512) {
    int r = i >> 9, c = i & 511;
    xs[r][c] = xb[(ROW_LO + r) * D + c];
  }
  __syncthreads();
  int half = tid >> 8;
  int p = tid & 255;
  int d = dg * 256 + p;
  int c = d + half * D;
  float acc[16];
  float bi = bias[c];
  #pragma unroll
  for (int l = 0; l < 16; ++l) acc[l] = bi;
  const float* wr = w + (size_t)c * (D * KSZ);
  for (int dp = 0; dp < D; ++dp) {
    float wk[KSZ];
    #pragma unroll
    for (int k = 0; k < KSZ; ++k) wk[k] = wr[dp * KSZ + k];
    #pragma unroll
    for (int jj = 0; jj < NROWS; ++jj) {
      float xv = xs[jj][dp];
      #pragma unroll
      for (int k = 0; k < KSZ; ++k) {
        int l = jj + ROW_LO + 6 - k;
        if (l >= L0 && l < L0 + 16) acc[l - L0] += xv * wk[k];
      }
    }
  }
  if (half) {
    #pragma unroll
    for (int l = 0; l < 16; ++l) sb[p][l] = acc[l];
  }
  __syncthreads();
  if (!half) {
    #pragma unroll
    for (int li = 0; li < 16; ++li) {
      float yb = sb[p][li];
      float g = acc[li] / (1.f + expf(-yb));
      int l = L0 + li;
      float res = xs[l - ROW_LO][d];
      xout[((size_t)b * L + l) * D + d] = g + res;
    }
  }
}

__global__ __launch_bounds__(512) void k_conv(const float* __restrict__ xin,
                                              const float* __restrict__ w,
                                              const float* __restrict__ bias,
                                              float* __restrict__ xout) {
  __shared__ float xs[22][512];
  __shared__ float sb[256][17];
  int b = blockIdx.x, lh = blockIdx.y, dg = blockIdx.z, tid = threadIdx.x;
  if (lh == 0) conv_body<0>(xin, w, bias, xout, b, dg, tid, xs, sb);
  else         conv_body<1>(xin, w, bias, xout, b, dg, tid, xs, sb);
}

// ---------------------------------------------------------------------------
// cbase[b,v] = b2[v] + ctx[b,:1024] . W2[v,:1024]
__global__ void k_cbase(const float* __restrict__ ctx, const float* __restrict__ W2,
                        const float* __restrict__ b2, float* __restrict__ cbase) {
  __shared__ float sc[32][256];
  int v = blockIdx.x * 256 + threadIdx.x;
  int b0 = blockIdx.y * 32;
  bool vok = v < V;
  int vc = vok ? v : V - 1;
  float acc[32];
  #pragma unroll
  for (int bb = 0; bb < 32; ++bb) acc[bb] = 0.f;
  for (int et = 0; et < 4; ++et) {
    __syncthreads();
    for (int i = threadIdx.x; i < 32 * 256; i += 256) {
      int bb = i >> 8;
      int e = i & 255;
      sc[bb][e] = ctx[(size_t)(b0 + bb) * E_ENC + et * 256 + e];
    }
    __syncthreads();
    const float* wrow = W2 + (size_t)vc * (E_ENC + D) + et * 256;
    for (int e = 0; e < 256; e += 4) {
      float4 w4 = *(const float4*)(wrow + e);
      #pragma unroll
      for (int bb = 0; bb < 32; ++bb)
        acc[bb] += w4.x * sc[bb][e] + w4.y * sc[bb][e + 1] + w4.z * sc[bb][e + 2] + w4.w * sc[bb][e + 3];
    }
  }
  if (vok) {
    float bias = b2[v];
    #pragma unroll
    for (int bb = 0; bb < 32; ++bb) cbase[(size_t)(b0 + bb) * V + v] = acc[bb] + bias;
  }
}

// ---------------------------------------------------------------------------
// bf16 conversions
__global__ void k_cvt_x3(const float* __restrict__ x, unsigned short* __restrict__ y) {
  int i = blockIdx.x * 256 + threadIdx.x;   // group of 4 elements; grid covers exactly
  float4 f = ((const float4*)x)[i];
  ushort4 o;
  o.x = f2bf(f.x); o.y = f2bf(f.y); o.z = f2bf(f.z); o.w = f2bf(f.w);
  ((ushort4*)y)[i] = o;
}

__global__ void k_cvt_w2d(const float* __restrict__ W2, unsigned short* __restrict__ y) {
  int i = blockIdx.x * 256 + threadIdx.x;   // 30000*128 groups of 4
  int row = i >> 7, c = (i & 127) << 2;
  float4 f = *(const float4*)(W2 + (size_t)row * (E_ENC + D) + E_ENC + c);
  ushort4 o;
  o.x = f2bf(f.x); o.y = f2bf(f.y); o.z = f2bf(f.z); o.w = f2bf(f.w);
  *(ushort4*)(y + (size_t)row * D + c) = o;
}

// ---------------------------------------------------------------------------
// logits[b,s,v] = cbase[b,v] + x3[b,s,:] . W2d[v,:]  (bf16 MFMA, m97 structure)
// M=2048 (g=b*32+l), N=30000, K=512. Tile 128x128, BK=32, 4 waves (2x2),
// each wave 64x64 = 4x4 fragments of 16x16x32.
__global__ __launch_bounds__(256) void k_logits_mfma(
    const unsigned short* __restrict__ Ab,   // x3 bf16 [2048][512]
    const unsigned short* __restrict__ Bb,   // W2d bf16 [30000][512]
    const float* __restrict__ cbase, float* __restrict__ out) {
  __shared__ __align__(16) unsigned short As[128 * 32];  // 8 KB, row-major [row][k]
  __shared__ __align__(16) unsigned short Bs[128 * 32];  // 8 KB, row-major [v][k]
  int v0 = blockIdx.x * 128, g0 = blockIdx.y * 128;
  int tid = threadIdx.x;
  int lane = tid & 63, wave = tid >> 6;
  int wr = wave >> 1, wc = wave & 1;

  f32x4 acc[4][4];
  #pragma unroll
  for (int m = 0; m < 4; ++m)
    #pragma unroll
    for (int n = 0; n < 4; ++n) acc[m][n] = (f32x4){0.f, 0.f, 0.f, 0.f};

  // staging: 512 chunks of 16B per tile; thread handles chunk tid and tid+256.
  // chunk c -> row c>>2, 8-elem segment c&3. LDS dst is wave-uniform base.
  int r1 = tid >> 2, s1 = tid & 3;
  unsigned short* aB1 = As + wave * 512;          // bytes: wave*1024
  unsigned short* aB2 = As + wave * 512 + 2048;   // + 4096 B
  unsigned short* bB1 = Bs + wave * 512;
  unsigned short* bB2 = Bs + wave * 512 + 2048;
  int vrow1 = v0 + r1;      if (vrow1 > V - 1) vrow1 = V - 1;
  int vrow2 = v0 + r1 + 64; if (vrow2 > V - 1) vrow2 = V - 1;
  const unsigned short* gA1 = Ab + (size_t)(g0 + r1) * 512 + s1 * 8;
  const unsigned short* gA2 = Ab + (size_t)(g0 + r1 + 64) * 512 + s1 * 8;
  const unsigned short* gB1 = Bb + (size_t)vrow1 * 512 + s1 * 8;
  const unsigned short* gB2 = Bb + (size_t)vrow2 * 512 + s1 * 8;

  int rsel = lane & 15, hi = lane >> 4;

  for (int kt = 0; kt < 16; ++kt) {
    gload_lds16(gA1, aB1);
    gload_lds16(gA2, aB2);
    gload_lds16(gB1, bB1);
    gload_lds16(gB2, bB2);
    gA1 += 32; gA2 += 32; gB1 += 32; gB2 += 32;
    __syncthreads();

    bf16x8 af[4], bfr[4];
    #pragma unroll
    for (int m = 0; m < 4; ++m)
      af[m] = *(const bf16x8*)(As + (wr * 64 + m * 16 + rsel) * 32 + hi * 8);
    #pragma unroll
    for (int n = 0; n < 4; ++n)
      bfr[n] = *(const bf16x8*)(Bs + (wc * 64 + n * 16 + rsel) * 32 + hi * 8);
    #pragma unroll
    for (int m = 0; m < 4; ++m)
      #pragma unroll
      for (int n = 0; n < 4; ++n)
        acc[m][n] = __builtin_amdgcn_mfma_f32_16x16x32_bf16(af[m], bfr[n], acc[m][n], 0, 0, 0);
    __syncthreads();
  }

  // epilogue: C/D layout col=lane&15, row=(lane>>4)*4+reg
  #pragma unroll
  for (int m = 0; m < 4; ++m) {
    #pragma unroll
    for (int i = 0; i < 4; ++i) {
      int g = g0 + wr * 64 + m * 16 + hi * 4 + i;
      int b = g >> 5, lt = g & 31;
      if (lt >= S) continue;
      size_t orow = ((size_t)b * S + lt) * V;
      const float* cb = cbase + (size_t)b * V;
      #pragma unroll
      for (int n = 0; n < 4; ++n) {
        int v = v0 + wc * 64 + n * 16 + rsel;
        if (v < V) out[orow + v] = acc[m][n][i] + cb[v];
      }
    }
  }
}

// ---------------------------------------------------------------------------
extern "C" void kernel_launch(void* const* d_in, const int* in_sizes, int n_in,
                              void* d_out, int out_size, void* d_ws, size_t ws_size,
                              hipStream_t stream) {
  const float* features = (const float*)d_in[0];
  const int*   captions = (const int*)d_in[1];
  const float* embed_W  = (const float*)d_in[3];
  const float* W1   = (const float*)d_in[4];
  const float* b1   = (const float*)d_in[5];
  const float* cw1  = (const float*)d_in[6];
  const float* cb1  = (const float*)d_in[7];
  const float* cw2  = (const float*)d_in[8];
  const float* cb2  = (const float*)d_in[9];
  const float* Wenc = (const float*)d_in[10];
  const float* benc = (const float*)d_in[11];
  const float* Wp   = (const float*)d_in[14];
  const float* W2   = (const float*)d_in[16];
  const float* b2   = (const float*)d_in[17];
  float* out = (float*)d_out;

  float* ws = (float*)d_ws;
  float* wv       = ws;               // 1024
  float* c0       = ws + 1024;        // 16
  float* enc_mean = ws + 1040;        // 65536
  float* ctx      = ws + 66576;       // 65536
  float* base1    = ws + 132112;      // 32768
  float* xA       = ws + 164880;      // 1048576  (x1, then x3)
  float* xB       = ws + 1213456;     // 1048576  (x2); reused for x3 bf16
  float* cbase    = ws + 2262032;     // 1920000
  unsigned short* W2d = (unsigned short*)(ws + 4182032);  // 15,360,000 bf16 = 7.68M floats
  unsigned short* x3b = (unsigned short*)xB;              // 1,048,576 bf16 (xB free by then)
  // total: 11,862,032 floats = 47.5 MB

  hipLaunchKernelGGL(k_cvt_w2d, dim3(15000),     dim3(256), 0, stream, W2, W2d);
  hipLaunchKernelGGL(k_wv,       dim3(4),        dim3(256), 0, stream, Wenc, Wp, benc, wv, c0);
  hipLaunchKernelGGL(k_mean_ctx, dim3(B),        dim3(256), 0, stream, features, wv, c0, enc_mean, ctx);
  hipLaunchKernelGGL(k_base1,    dim3(B),        dim3(256), 0, stream, enc_mean, W1, b1, base1);
  hipLaunchKernelGGL(k_x1,       dim3(B),        dim3(256), 0, stream, embed_W, captions, W1, base1, xA);
  hipLaunchKernelGGL(k_conv,     dim3(B, 2, 2),  dim3(512), 0, stream, xA, cw1, cb1, xB);
  hipLaunchKernelGGL(k_conv,     dim3(B, 2, 2),  dim3(512), 0, stream, xB, cw2, cb2, xA);
  hipLaunchKernelGGL(k_cvt_x3,   dim3(1024),     dim3(256), 0, stream, xA, x3b);
  hipLaunchKernelGGL(k_cbase,    dim3(118, 2),   dim3(256), 0, stream, ctx, W2, b2, cbase);
  hipLaunchKernelGGL(k_logits_mfma, dim3(235, 16), dim3(256), 0, stream, x3b, W2d, cbase, out);
}

// Round 3
// 863.470 us; speedup vs baseline: 3.0316x; 1.7017x over previous
//
#include <hip/hip_runtime.h>
#include <hip/hip_bf16.h>
#include <math.h>

// Sizes (fixed by the problem)
#define B 64
#define T 64
#define E_ENC 1024
#define EMB 512
#define D 512
#define L 32
#define S 31
#define A 512
#define V 30000
#define KSZ 7
#define KC (D * KSZ)   // 3584 = conv GEMM K

typedef __attribute__((ext_vector_type(8))) short bf16x8;
typedef __attribute__((ext_vector_type(4))) float f32x4;

__device__ __forceinline__ unsigned short f2bf(float f) {
  union { float f; unsigned int u; } x; x.f = f;
  unsigned int r = (x.u + 0x7fffu + ((x.u >> 16) & 1u)) >> 16;
  return (unsigned short)r;
}

__device__ __forceinline__ void gload_lds16(const void* g, void* l) {
  __builtin_amdgcn_global_load_lds(
      (const __attribute__((address_space(1))) unsigned int*)g,
      (__attribute__((address_space(3))) unsigned int*)l, 16, 0, 0);
}

// ---------------------------------------------------------------------------
// wv[e] = sum_a Wp[a]*Wenc[a,e];  c0 = sum_a benc[a]*Wp[a]
__global__ void k_wv(const float* __restrict__ Wenc, const float* __restrict__ Wp,
                     const float* __restrict__ benc, float* __restrict__ wv,
                     float* __restrict__ c0) {
  __shared__ float red[256];
  int e = blockIdx.x * 256 + threadIdx.x;
  float s = 0.f;
  for (int a = 0; a < A; ++a) s += Wp[a] * Wenc[(size_t)a * E_ENC + e];
  wv[e] = s;
  if (blockIdx.x == 0) {
    int t = threadIdx.x;
    float v = Wp[t] * benc[t] + Wp[t + 256] * benc[t + 256];
    red[t] = v;
    __syncthreads();
    for (int off = 128; off > 0; off >>= 1) {
      if (t < off) red[t] += red[t + off];
      __syncthreads();
    }
    if (t == 0) c0[0] = red[0];
  }
}

// ---------------------------------------------------------------------------
// Per-b: enc_mean[b,:], fscore -> softmax over t -> ctx[b,:]
__global__ void k_mean_ctx(const float* __restrict__ features, const float* __restrict__ wv,
                           const float* __restrict__ c0, float* __restrict__ enc_mean,
                           float* __restrict__ ctx) {
  int b = blockIdx.x, tid = threadIdx.x;
  const float* fb = features + (size_t)b * T * E_ENC;
  __shared__ float s_attw[T];

  float m0 = 0, m1 = 0, m2 = 0, m3 = 0;
  for (int t = 0; t < T; ++t) {
    const float* r = fb + t * E_ENC;
    m0 += r[tid]; m1 += r[tid + 256]; m2 += r[tid + 512]; m3 += r[tid + 768];
  }
  size_t eb = (size_t)b * E_ENC;
  enc_mean[eb + tid]       = m0 * (1.f / 64.f);
  enc_mean[eb + tid + 256] = m1 * (1.f / 64.f);
  enc_mean[eb + tid + 512] = m2 * (1.f / 64.f);
  enc_mean[eb + tid + 768] = m3 * (1.f / 64.f);

  {
    int t = tid >> 2, part = tid & 3;
    const float* r = fb + t * E_ENC + part * 256;
    const float* wp = wv + part * 256;
    float s = 0.f;
    for (int e = 0; e < 256; e += 4) {
      float4 f4 = *(const float4*)(r + e);
      float4 w4 = *(const float4*)(wp + e);
      s += f4.x * w4.x + f4.y * w4.y + f4.z * w4.z + f4.w * w4.w;
    }
    s += __shfl_xor(s, 1);
    s += __shfl_xor(s, 2);
    if (part == 0) s_attw[t] = s + c0[0];
  }
  __syncthreads();
  if (tid < 64) {
    float v = s_attw[tid];
    float mx = v;
    #pragma unroll
    for (int off = 32; off > 0; off >>= 1) mx = fmaxf(mx, __shfl_xor(mx, off));
    float e = expf(v - mx);
    float sm = e;
    #pragma unroll
    for (int off = 32; off > 0; off >>= 1) sm += __shfl_xor(sm, off);
    s_attw[tid] = e / sm;
  }
  __syncthreads();
  float ca = 0, cb = 0, cc = 0, cd = 0;
  for (int t = 0; t < T; ++t) {
    float w = s_attw[t];
    const float* r = fb + t * E_ENC;
    ca += w * r[tid]; cb += w * r[tid + 256]; cc += w * r[tid + 512]; cd += w * r[tid + 768];
  }
  ctx[eb + tid]       = ca;
  ctx[eb + tid + 256] = cb;
  ctx[eb + tid + 512] = cc;
  ctx[eb + tid + 768] = cd;
}

// ---------------------------------------------------------------------------
// base1[b,d] = b1[d] + enc_mean[b,:1024] . W1[d,:1024]
__global__ void k_base1(const float* __restrict__ enc_mean, const float* __restrict__ W1,
                        const float* __restrict__ b1, float* __restrict__ base1) {
  __shared__ float em[E_ENC];
  int b = blockIdx.x, tid = threadIdx.x;
  for (int i = tid; i < E_ENC; i += 256) em[i] = enc_mean[(size_t)b * E_ENC + i];
  __syncthreads();
  for (int d = tid; d < D; d += 256) {
    const float* w = W1 + (size_t)d * (E_ENC + EMB);
    float acc = 0.f;
    for (int e = 0; e < E_ENC; e += 4) {
      float4 w4 = *(const float4*)(w + e);
      acc += w4.x * em[e] + w4.y * em[e + 1] + w4.z * em[e + 2] + w4.w * em[e + 3];
    }
    base1[b * D + d] = acc + b1[d];
  }
}

// ---------------------------------------------------------------------------
// x1[b,l,d] = base1[b,d] + emb[captions[b,l],:] . W1[d,1024:1536]
__global__ void k_x1(const float* __restrict__ embed_W, const int* __restrict__ captions,
                     const float* __restrict__ W1, const float* __restrict__ base1,
                     float* __restrict__ x1) {
  __shared__ float emb[L][EMB];  // 64 KiB
  int b = blockIdx.x, tid = threadIdx.x;
  for (int i = tid; i < L * EMB; i += 256) {
    int l = i >> 9, c = i & 511;
    emb[l][c] = embed_W[(size_t)captions[b * L + l] * EMB + c];
  }
  __syncthreads();
  for (int d = tid; d < D; d += 256) {
    const float* wrow = W1 + (size_t)d * (E_ENC + EMB) + E_ENC;
    float acc[L];
    #pragma unroll
    for (int l = 0; l < L; ++l) acc[l] = 0.f;
    for (int e = 0; e < EMB; ++e) {
      float we = wrow[e];
      #pragma unroll
      for (int l = 0; l < L; ++l) acc[l] += we * emb[l][e];
    }
    float bb = base1[b * D + d];
    #pragma unroll
    for (int l = 0; l < L; ++l) x1[((size_t)b * L + l) * D + d] = acc[l] + bb;
  }
}

// ---------------------------------------------------------------------------
// im2col: Xc[g][k*512+dp] = (l+k-6 >= 0) ? x[b][l+k-6][dp] : 0   (bf16)
// grid 2048 blocks x 256 threads; each thread 2 dp per k, coalesced.
__global__ void k_im2col(const float* __restrict__ x, unsigned short* __restrict__ Xc) {
  int g = blockIdx.x, tid = threadIdx.x;
  int b = g >> 5, l = g & 31;
  unsigned short* row = Xc + (size_t)g * KC;
  const float* xb = x + (size_t)b * L * D;
  int d = tid * 2;
  #pragma unroll
  for (int k = 0; k < KSZ; ++k) {
    int lp = l + k - 6;
    unsigned int pk = 0;
    if (lp >= 0) {
      float2 v = *(const float2*)(xb + (size_t)lp * D + d);
      pk = (unsigned int)f2bf(v.x) | ((unsigned int)f2bf(v.y) << 16);
    }
    *(unsigned int*)(row + k * 512 + d) = pk;
  }
}

// ---------------------------------------------------------------------------
// conv weight reorder+convert: wb[c][k*512+dp] = bf16(w[c][dp*7+k])
__global__ void k_cvt_wconv(const float* __restrict__ w, unsigned short* __restrict__ wb) {
  __shared__ float row[KC];  // 14 KiB
  int c = blockIdx.x, tid = threadIdx.x;
  const float* wr = w + (size_t)c * KC;
  for (int i = tid; i < KC; i += 256) row[i] = wr[i];
  __syncthreads();
  unsigned short* ob = wb + (size_t)c * KC;
  int dp = tid * 2;
  #pragma unroll
  for (int k = 0; k < KSZ; ++k) {
    unsigned int pk = (unsigned int)f2bf(row[dp * 7 + k]) |
                      ((unsigned int)f2bf(row[(dp + 1) * 7 + k]) << 16);
    *(unsigned int*)(ob + k * 512 + dp) = pk;
  }
}

// ---------------------------------------------------------------------------
// Conv GEMM: y[g][c] = bias[c] + Xc[g,:] . wb[c,:]   M=2048, N=1024, K=3584
// 64x64 tile, BK=64, 4 waves (2x2), 2x2 frags/wave. XOR slot swizzle
// (slot ^= row&7) applied on the GLOBAL source (gload_lds dst is linear) and
// on the ds_read address — spreads the 128B-row conflict across 8 banksets.
__global__ __launch_bounds__(256) void k_conv_mfma(
    const unsigned short* __restrict__ Xc, const unsigned short* __restrict__ wb,
    const float* __restrict__ bias, float* __restrict__ y) {
  __shared__ __align__(16) unsigned short As[64 * 64];  // 8 KB
  __shared__ __align__(16) unsigned short Bs[64 * 64];  // 8 KB
  int c0 = blockIdx.x * 64, g0 = blockIdx.y * 64;
  int tid = threadIdx.x, lane = tid & 63, wave = tid >> 6;
  int wr = wave >> 1, wc = wave & 1;
  int rsel = lane & 15, hi = lane >> 4;

  f32x4 acc[2][2];
  #pragma unroll
  for (int m = 0; m < 2; ++m)
    #pragma unroll
    for (int n = 0; n < 2; ++n) acc[m][n] = (f32x4){0.f, 0.f, 0.f, 0.f};

  // staging: chunk q -> row q>>3, slot q&7 (16B each). thread: q=tid, q=tid+256.
  int r1 = tid >> 3, s1 = tid & 7;
  int sw = (s1 ^ (r1 & 7)) * 8;              // swizzled global k-segment (shorts)
  const unsigned short* gA1 = Xc + (size_t)(g0 + r1) * KC + sw;
  const unsigned short* gA2 = Xc + (size_t)(g0 + r1 + 32) * KC + sw;
  const unsigned short* gB1 = wb + (size_t)(c0 + r1) * KC + sw;
  const unsigned short* gB2 = wb + (size_t)(c0 + r1 + 32) * KC + sw;
  unsigned short* aD1 = As + wave * 512;
  unsigned short* aD2 = As + 2048 + wave * 512;
  unsigned short* bD1 = Bs + wave * 512;
  unsigned short* bD2 = Bs + 2048 + wave * 512;

  int slot0 = hi ^ (rsel & 7);        // kk=0
  int slot1 = (4 + hi) ^ (rsel & 7);  // kk=1

  for (int kt = 0; kt < KC / 64; ++kt) {
    gload_lds16(gA1, aD1);
    gload_lds16(gA2, aD2);
    gload_lds16(gB1, bD1);
    gload_lds16(gB2, bD2);
    gA1 += 64; gA2 += 64; gB1 += 64; gB2 += 64;
    __syncthreads();

    bf16x8 af[2][2], bfr[2][2];
    #pragma unroll
    for (int m = 0; m < 2; ++m) {
      int rowA = (wr * 32 + m * 16 + rsel) * 64;
      af[m][0] = *(const bf16x8*)(As + rowA + slot0 * 8);
      af[m][1] = *(const bf16x8*)(As + rowA + slot1 * 8);
    }
    #pragma unroll
    for (int n = 0; n < 2; ++n) {
      int rowB = (wc * 32 + n * 16 + rsel) * 64;
      bfr[n][0] = *(const bf16x8*)(Bs + rowB + slot0 * 8);
      bfr[n][1] = *(const bf16x8*)(Bs + rowB + slot1 * 8);
    }
    #pragma unroll
    for (int m = 0; m < 2; ++m)
      #pragma unroll
      for (int n = 0; n < 2; ++n) {
        acc[m][n] = __builtin_amdgcn_mfma_f32_16x16x32_bf16(af[m][0], bfr[n][0], acc[m][n], 0, 0, 0);
        acc[m][n] = __builtin_amdgcn_mfma_f32_16x16x32_bf16(af[m][1], bfr[n][1], acc[m][n], 0, 0, 0);
      }
    __syncthreads();
  }

  float bv[2];
  #pragma unroll
  for (int n = 0; n < 2; ++n) bv[n] = bias[c0 + wc * 32 + n * 16 + rsel];
  #pragma unroll
  for (int m = 0; m < 2; ++m)
    #pragma unroll
    for (int i = 0; i < 4; ++i) {
      int g = g0 + wr * 32 + m * 16 + hi * 4 + i;
      float* yr = y + (size_t)g * 1024;
      #pragma unroll
      for (int n = 0; n < 2; ++n)
        yr[c0 + wc * 32 + n * 16 + rsel] = acc[m][n][i] + bv[n];
    }
}

// ---------------------------------------------------------------------------
// GLU: xout[g][d] = y[g][d] * sigmoid(y[g][d+512]) + xres[g][d]
__global__ void k_glu(const float* __restrict__ y, const float* __restrict__ xres,
                      float* __restrict__ xout) {
  int idx = blockIdx.x * 256 + threadIdx.x;  // 2048*128
  int g = idx >> 7, d4 = (idx & 127) << 2;
  const float* yr = y + (size_t)g * 1024;
  float4 a = *(const float4*)(yr + d4);
  float4 bq = *(const float4*)(yr + 512 + d4);
  float4 xr = *(const float4*)(xres + (size_t)g * 512 + d4);
  float4 o;
  o.x = a.x / (1.f + expf(-bq.x)) + xr.x;
  o.y = a.y / (1.f + expf(-bq.y)) + xr.y;
  o.z = a.z / (1.f + expf(-bq.z)) + xr.z;
  o.w = a.w / (1.f + expf(-bq.w)) + xr.w;
  *(float4*)(xout + (size_t)g * 512 + d4) = o;
}

// Layer-2 GLU: writes bf16 x3 directly (decode only feeds the logits GEMM).
__global__ void k_glu_bf16(const float* __restrict__ y, const float* __restrict__ xres,
                           unsigned short* __restrict__ xout) {
  int idx = blockIdx.x * 256 + threadIdx.x;
  int g = idx >> 7, d4 = (idx & 127) << 2;
  const float* yr = y + (size_t)g * 1024;
  float4 a = *(const float4*)(yr + d4);
  float4 bq = *(const float4*)(yr + 512 + d4);
  float4 xr = *(const float4*)(xres + (size_t)g * 512 + d4);
  ushort4 o;
  o.x = f2bf(a.x / (1.f + expf(-bq.x)) + xr.x);
  o.y = f2bf(a.y / (1.f + expf(-bq.y)) + xr.y);
  o.z = f2bf(a.z / (1.f + expf(-bq.z)) + xr.z);
  o.w = f2bf(a.w / (1.f + expf(-bq.w)) + xr.w);
  *(ushort4*)(xout + (size_t)g * 512 + d4) = o;
}

// ---------------------------------------------------------------------------
// cbase[b,v] = b2[v] + ctx[b,:1024] . W2[v,:1024]   (fp32)
__global__ void k_cbase(const float* __restrict__ ctx, const float* __restrict__ W2,
                        const float* __restrict__ b2, float* __restrict__ cbase) {
  __shared__ float sc[32][256];
  int v = blockIdx.x * 256 + threadIdx.x;
  int b0 = blockIdx.y * 32;
  bool vok = v < V;
  int vc = vok ? v : V - 1;
  float acc[32];
  #pragma unroll
  for (int bb = 0; bb < 32; ++bb) acc[bb] = 0.f;
  for (int et = 0; et < 4; ++et) {
    __syncthreads();
    for (int i = threadIdx.x; i < 32 * 256; i += 256) {
      int bb = i >> 8;
      int e = i & 255;
      sc[bb][e] = ctx[(size_t)(b0 + bb) * E_ENC + et * 256 + e];
    }
    __syncthreads();
    const float* wrow = W2 + (size_t)vc * (E_ENC + D) + et * 256;
    for (int e = 0; e < 256; e += 4) {
      float4 w4 = *(const float4*)(wrow + e);
      #pragma unroll
      for (int bb = 0; bb < 32; ++bb)
        acc[bb] += w4.x * sc[bb][e] + w4.y * sc[bb][e + 1] + w4.z * sc[bb][e + 2] + w4.w * sc[bb][e + 3];
    }
  }
  if (vok) {
    float bias = b2[v];
    #pragma unroll
    for (int bb = 0; bb < 32; ++bb) cbase[(size_t)(b0 + bb) * V + v] = acc[bb] + bias;
  }
}

// ---------------------------------------------------------------------------
// W2 decode-half conversion: y[v][c] = bf16(W2[v][1024+c])
__global__ void k_cvt_w2d(const float* __restrict__ W2, unsigned short* __restrict__ y) {
  int i = blockIdx.x * 256 + threadIdx.x;   // 30000*128 groups of 4
  int row = i >> 7, c = (i & 127) << 2;
  float4 f = *(const float4*)(W2 + (size_t)row * (E_ENC + D) + E_ENC + c);
  ushort4 o;
  o.x = f2bf(f.x); o.y = f2bf(f.y); o.z = f2bf(f.z); o.w = f2bf(f.w);
  *(ushort4*)(y + (size_t)row * D + c) = o;
}

// ---------------------------------------------------------------------------
// logits[b,s,v] = cbase[b,v] + x3[b,s,:] . W2d[v,:]  (bf16 MFMA, m97 structure)
__global__ __launch_bounds__(256) void k_logits_mfma(
    const unsigned short* __restrict__ Ab,   // x3 bf16 [2048][512]
    const unsigned short* __restrict__ Bb,   // W2d bf16 [30000][512]
    const float* __restrict__ cbase, float* __restrict__ out) {
  __shared__ __align__(16) unsigned short As[128 * 32];
  __shared__ __align__(16) unsigned short Bs[128 * 32];
  int v0 = blockIdx.x * 128, g0 = blockIdx.y * 128;
  int tid = threadIdx.x;
  int lane = tid & 63, wave = tid >> 6;
  int wr = wave >> 1, wc = wave & 1;

  f32x4 acc[4][4];
  #pragma unroll
  for (int m = 0; m < 4; ++m)
    #pragma unroll
    for (int n = 0; n < 4; ++n) acc[m][n] = (f32x4){0.f, 0.f, 0.f, 0.f};

  int r1 = tid >> 2, s1 = tid & 3;
  unsigned short* aB1 = As + wave * 512;
  unsigned short* aB2 = As + wave * 512 + 2048;
  unsigned short* bB1 = Bs + wave * 512;
  unsigned short* bB2 = Bs + wave * 512 + 2048;
  int vrow1 = v0 + r1;      if (vrow1 > V - 1) vrow1 = V - 1;
  int vrow2 = v0 + r1 + 64; if (vrow2 > V - 1) vrow2 = V - 1;
  const unsigned short* gA1 = Ab + (size_t)(g0 + r1) * 512 + s1 * 8;
  const unsigned short* gA2 = Ab + (size_t)(g0 + r1 + 64) * 512 + s1 * 8;
  const unsigned short* gB1 = Bb + (size_t)vrow1 * 512 + s1 * 8;
  const unsigned short* gB2 = Bb + (size_t)vrow2 * 512 + s1 * 8;

  int rsel = lane & 15, hi = lane >> 4;

  for (int kt = 0; kt < 16; ++kt) {
    gload_lds16(gA1, aB1);
    gload_lds16(gA2, aB2);
    gload_lds16(gB1, bB1);
    gload_lds16(gB2, bB2);
    gA1 += 32; gA2 += 32; gB1 += 32; gB2 += 32;
    __syncthreads();

    bf16x8 af[4], bfr[4];
    #pragma unroll
    for (int m = 0; m < 4; ++m)
      af[m] = *(const bf16x8*)(As + (wr * 64 + m * 16 + rsel) * 32 + hi * 8);
    #pragma unroll
    for (int n = 0; n < 4; ++n)
      bfr[n] = *(const bf16x8*)(Bs + (wc * 64 + n * 16 + rsel) * 32 + hi * 8);
    #pragma unroll
    for (int m = 0; m < 4; ++m)
      #pragma unroll
      for (int n = 0; n < 4; ++n)
        acc[m][n] = __builtin_amdgcn_mfma_f32_16x16x32_bf16(af[m], bfr[n], acc[m][n], 0, 0, 0);
    __syncthreads();
  }

  #pragma unroll
  for (int m = 0; m < 4; ++m) {
    #pragma unroll
    for (int i = 0; i < 4; ++i) {
      int g = g0 + wr * 64 + m * 16 + hi * 4 + i;
      int b = g >> 5, lt = g & 31;
      if (lt >= S) continue;
      size_t orow = ((size_t)b * S + lt) * V;
      const float* cb = cbase + (size_t)b * V;
      #pragma unroll
      for (int n = 0; n < 4; ++n) {
        int v = v0 + wc * 64 + n * 16 + rsel;
        if (v < V) out[orow + v] = acc[m][n][i] + cb[v];
      }
    }
  }
}

// ---------------------------------------------------------------------------
extern "C" void kernel_launch(void* const* d_in, const int* in_sizes, int n_in,
                              void* d_out, int out_size, void* d_ws, size_t ws_size,
                              hipStream_t stream) {
  const float* features = (const float*)d_in[0];
  const int*   captions = (const int*)d_in[1];
  const float* embed_W  = (const float*)d_in[3];
  const float* W1   = (const float*)d_in[4];
  const float* b1   = (const float*)d_in[5];
  const float* cw1  = (const float*)d_in[6];
  const float* cb1  = (const float*)d_in[7];
  const float* cw2  = (const float*)d_in[8];
  const float* cb2  = (const float*)d_in[9];
  const float* Wenc = (const float*)d_in[10];
  const float* benc = (const float*)d_in[11];
  const float* Wp   = (const float*)d_in[14];
  const float* W2   = (const float*)d_in[16];
  const float* b2   = (const float*)d_in[17];
  float* out = (float*)d_out;

  float* ws = (float*)d_ws;
  float* wv       = ws;                 // 1024
  float* c0       = ws + 1024;          // 16
  float* enc_mean = ws + 1040;          // 65536
  float* ctx      = ws + 66576;         // 65536
  float* base1    = ws + 132112;        // 32768
  float* xA       = ws + 164880;        // 1048576 (x1; dead after GLU1)
  float* xB       = ws + 1213456;       // 1048576 (x2)
  float* y        = ws + 2262032;       // 2097152 (conv GEMM out; cbase aliases after)
  float* cbase    = y;                  // 1920000 <= 2097152, y dead by then
  unsigned short* x3b  = (unsigned short*)xA;            // 1048576 bf16 (xA dead)
  unsigned short* Xc   = (unsigned short*)(ws + 4359184); // 7340032 bf16
  unsigned short* wbuf = (unsigned short*)(ws + 8029200); // 3670016 bf16 (reused both layers)
  unsigned short* W2d  = (unsigned short*)(ws + 9864208); // 15360000 bf16
  // end: 17,544,208 floats = 70.2 MB

  hipLaunchKernelGGL(k_cvt_w2d,  dim3(15000),   dim3(256), 0, stream, W2, W2d);
  hipLaunchKernelGGL(k_wv,       dim3(4),       dim3(256), 0, stream, Wenc, Wp, benc, wv, c0);
  hipLaunchKernelGGL(k_mean_ctx, dim3(B),       dim3(256), 0, stream, features, wv, c0, enc_mean, ctx);
  hipLaunchKernelGGL(k_base1,    dim3(B),       dim3(256), 0, stream, enc_mean, W1, b1, base1);
  hipLaunchKernelGGL(k_x1,       dim3(B),       dim3(256), 0, stream, embed_W, captions, W1, base1, xA);

  // conv layer 1
  hipLaunchKernelGGL(k_cvt_wconv, dim3(1024),   dim3(256), 0, stream, cw1, wbuf);
  hipLaunchKernelGGL(k_im2col,    dim3(2048),   dim3(256), 0, stream, xA, Xc);
  hipLaunchKernelGGL(k_conv_mfma, dim3(16, 32), dim3(256), 0, stream, Xc, wbuf, cb1, y);
  hipLaunchKernelGGL(k_glu,       dim3(1024),   dim3(256), 0, stream, y, xA, xB);

  // conv layer 2
  hipLaunchKernelGGL(k_cvt_wconv, dim3(1024),   dim3(256), 0, stream, cw2, wbuf);
  hipLaunchKernelGGL(k_im2col,    dim3(2048),   dim3(256), 0, stream, xB, Xc);
  hipLaunchKernelGGL(k_conv_mfma, dim3(16, 32), dim3(256), 0, stream, Xc, wbuf, cb2, y);
  hipLaunchKernelGGL(k_glu_bf16,  dim3(1024),   dim3(256), 0, stream, y, xB, x3b);

  hipLaunchKernelGGL(k_cbase,    dim3(118, 2),  dim3(256), 0, stream, ctx, W2, b2, cbase);
  hipLaunchKernelGGL(k_logits_mfma, dim3(235, 16), dim3(256), 0, stream, x3b, W2d, cbase, out);
}

// Round 4
// 649.712 us; speedup vs baseline: 4.0290x; 1.3290x over previous
//
#include <hip/hip_runtime.h>
#include <hip/hip_bf16.h>
#include <math.h>

// Sizes (fixed by the problem)
#define B 64
#define T 64
#define E_ENC 1024
#define EMB 512
#define D 512
#define L 32
#define S 31
#define A 512
#define V 30000
#define KSZ 7
#define KC (D * KSZ)   // 3584 = conv GEMM K

typedef __attribute__((ext_vector_type(8))) short bf16x8;
typedef __attribute__((ext_vector_type(4))) float f32x4;

__device__ __forceinline__ unsigned short f2bf(float f) {
  union { float f; unsigned int u; } x; x.f = f;
  unsigned int r = (x.u + 0x7fffu + ((x.u >> 16) & 1u)) >> 16;
  return (unsigned short)r;
}

__device__ __forceinline__ void gload_lds16(const void* g, void* l) {
  __builtin_amdgcn_global_load_lds(
      (const __attribute__((address_space(1))) unsigned int*)g,
      (__attribute__((address_space(3))) unsigned int*)l, 16, 0, 0);
}

// ---------------------------------------------------------------------------
// wv[e] = sum_a Wp[a]*Wenc[a,e];  c0 = sum_a benc[a]*Wp[a]
__global__ void k_wv(const float* __restrict__ Wenc, const float* __restrict__ Wp,
                     const float* __restrict__ benc, float* __restrict__ wv,
                     float* __restrict__ c0) {
  __shared__ float red[256];
  int e = blockIdx.x * 256 + threadIdx.x;
  float s = 0.f;
  for (int a = 0; a < A; ++a) s += Wp[a] * Wenc[(size_t)a * E_ENC + e];
  wv[e] = s;
  if (blockIdx.x == 0) {
    int t = threadIdx.x;
    float v = Wp[t] * benc[t] + Wp[t + 256] * benc[t + 256];
    red[t] = v;
    __syncthreads();
    for (int off = 128; off > 0; off >>= 1) {
      if (t < off) red[t] += red[t + off];
      __syncthreads();
    }
    if (t == 0) c0[0] = red[0];
  }
}

// ---------------------------------------------------------------------------
// Per-b: enc_mean[b,:], fscore -> softmax over t -> ctx (bf16)
__global__ void k_mean_ctx(const float* __restrict__ features, const float* __restrict__ wv,
                           const float* __restrict__ c0, float* __restrict__ enc_mean,
                           unsigned short* __restrict__ ctxb) {
  int b = blockIdx.x, tid = threadIdx.x;
  const float* fb = features + (size_t)b * T * E_ENC;
  __shared__ float s_attw[T];

  float m0 = 0, m1 = 0, m2 = 0, m3 = 0;
  for (int t = 0; t < T; ++t) {
    const float* r = fb + t * E_ENC;
    m0 += r[tid]; m1 += r[tid + 256]; m2 += r[tid + 512]; m3 += r[tid + 768];
  }
  size_t eb = (size_t)b * E_ENC;
  enc_mean[eb + tid]       = m0 * (1.f / 64.f);
  enc_mean[eb + tid + 256] = m1 * (1.f / 64.f);
  enc_mean[eb + tid + 512] = m2 * (1.f / 64.f);
  enc_mean[eb + tid + 768] = m3 * (1.f / 64.f);

  {
    int t = tid >> 2, part = tid & 3;
    const float* r = fb + t * E_ENC + part * 256;
    const float* wp = wv + part * 256;
    float s = 0.f;
    for (int e = 0; e < 256; e += 4) {
      float4 f4 = *(const float4*)(r + e);
      float4 w4 = *(const float4*)(wp + e);
      s += f4.x * w4.x + f4.y * w4.y + f4.z * w4.z + f4.w * w4.w;
    }
    s += __shfl_xor(s, 1);
    s += __shfl_xor(s, 2);
    if (part == 0) s_attw[t] = s + c0[0];
  }
  __syncthreads();
  if (tid < 64) {
    float v = s_attw[tid];
    float mx = v;
    #pragma unroll
    for (int off = 32; off > 0; off >>= 1) mx = fmaxf(mx, __shfl_xor(mx, off));
    float e = expf(v - mx);
    float sm = e;
    #pragma unroll
    for (int off = 32; off > 0; off >>= 1) sm += __shfl_xor(sm, off);
    s_attw[tid] = e / sm;
  }
  __syncthreads();
  float ca = 0, cb = 0, cc = 0, cd = 0;
  for (int t = 0; t < T; ++t) {
    float w = s_attw[t];
    const float* r = fb + t * E_ENC;
    ca += w * r[tid]; cb += w * r[tid + 256]; cc += w * r[tid + 512]; cd += w * r[tid + 768];
  }
  ctxb[eb + tid]       = f2bf(ca);
  ctxb[eb + tid + 256] = f2bf(cb);
  ctxb[eb + tid + 512] = f2bf(cc);
  ctxb[eb + tid + 768] = f2bf(cd);
}

// ---------------------------------------------------------------------------
// base1[b,d] = b1[d] + enc_mean[b,:1024] . W1[d,:1024]
__global__ void k_base1(const float* __restrict__ enc_mean, const float* __restrict__ W1,
                        const float* __restrict__ b1, float* __restrict__ base1) {
  __shared__ float em[E_ENC];
  int b = blockIdx.x, tid = threadIdx.x;
  for (int i = tid; i < E_ENC; i += 256) em[i] = enc_mean[(size_t)b * E_ENC + i];
  __syncthreads();
  for (int d = tid; d < D; d += 256) {
    const float* w = W1 + (size_t)d * (E_ENC + EMB);
    float acc = 0.f;
    for (int e = 0; e < E_ENC; e += 4) {
      float4 w4 = *(const float4*)(w + e);
      acc += w4.x * em[e] + w4.y * em[e + 1] + w4.z * em[e + 2] + w4.w * em[e + 3];
    }
    base1[b * D + d] = acc + b1[d];
  }
}

// ---------------------------------------------------------------------------
// x1[b,l,d] = base1[b,d] + emb[captions[b,l],:] . W1[d,1024:1536]
__global__ void k_x1(const float* __restrict__ embed_W, const int* __restrict__ captions,
                     const float* __restrict__ W1, const float* __restrict__ base1,
                     float* __restrict__ x1) {
  __shared__ float emb[L][EMB];  // 64 KiB
  int b = blockIdx.x, tid = threadIdx.x;
  for (int i = tid; i < L * EMB; i += 256) {
    int l = i >> 9, c = i & 511;
    emb[l][c] = embed_W[(size_t)captions[b * L + l] * EMB + c];
  }
  __syncthreads();
  for (int d = tid; d < D; d += 256) {
    const float* wrow = W1 + (size_t)d * (E_ENC + EMB) + E_ENC;
    float acc[L];
    #pragma unroll
    for (int l = 0; l < L; ++l) acc[l] = 0.f;
    for (int e = 0; e < EMB; ++e) {
      float we = wrow[e];
      #pragma unroll
      for (int l = 0; l < L; ++l) acc[l] += we * emb[l][e];
    }
    float bb = base1[b * D + d];
    #pragma unroll
    for (int l = 0; l < L; ++l) x1[((size_t)b * L + l) * D + d] = acc[l] + bb;
  }
}

// ---------------------------------------------------------------------------
// im2col: Xc[g][k*512+dp] = (l+k-6 >= 0) ? x[b][l+k-6][dp] : 0   (bf16)
__global__ void k_im2col(const float* __restrict__ x, unsigned short* __restrict__ Xc) {
  int g = blockIdx.x, tid = threadIdx.x;
  int b = g >> 5, l = g & 31;
  unsigned short* row = Xc + (size_t)g * KC;
  const float* xb = x + (size_t)b * L * D;
  int d = tid * 2;
  #pragma unroll
  for (int k = 0; k < KSZ; ++k) {
    int lp = l + k - 6;
    unsigned int pk = 0;
    if (lp >= 0) {
      float2 v = *(const float2*)(xb + (size_t)lp * D + d);
      pk = (unsigned int)f2bf(v.x) | ((unsigned int)f2bf(v.y) << 16);
    }
    *(unsigned int*)(row + k * 512 + d) = pk;
  }
}

// ---------------------------------------------------------------------------
// conv weight reorder+convert: wb[c][k*512+dp] = bf16(w[c][dp*7+k])
__global__ void k_cvt_wconv(const float* __restrict__ w, unsigned short* __restrict__ wb) {
  __shared__ float row[KC];  // 14 KiB
  int c = blockIdx.x, tid = threadIdx.x;
  const float* wr = w + (size_t)c * KC;
  for (int i = tid; i < KC; i += 256) row[i] = wr[i];
  __syncthreads();
  unsigned short* ob = wb + (size_t)c * KC;
  int dp = tid * 2;
  #pragma unroll
  for (int k = 0; k < KSZ; ++k) {
    unsigned int pk = (unsigned int)f2bf(row[dp * 7 + k]) |
                      ((unsigned int)f2bf(row[(dp + 1) * 7 + k]) << 16);
    *(unsigned int*)(ob + k * 512 + dp) = pk;
  }
}

// ---------------------------------------------------------------------------
// Conv GEMM: y[g][c] = bias[c] + Xc[g,:] . wb[c,:]   M=2048, N=1024, K=3584
__global__ __launch_bounds__(256) void k_conv_mfma(
    const unsigned short* __restrict__ Xc, const unsigned short* __restrict__ wb,
    const float* __restrict__ bias, float* __restrict__ y) {
  __shared__ __align__(16) unsigned short As[64 * 64];  // 8 KB
  __shared__ __align__(16) unsigned short Bs[64 * 64];  // 8 KB
  int c0 = blockIdx.x * 64, g0 = blockIdx.y * 64;
  int tid = threadIdx.x, lane = tid & 63, wave = tid >> 6;
  int wr = wave >> 1, wc = wave & 1;
  int rsel = lane & 15, hi = lane >> 4;

  f32x4 acc[2][2];
  #pragma unroll
  for (int m = 0; m < 2; ++m)
    #pragma unroll
    for (int n = 0; n < 2; ++n) acc[m][n] = (f32x4){0.f, 0.f, 0.f, 0.f};

  int r1 = tid >> 3, s1 = tid & 7;
  int sw = (s1 ^ (r1 & 7)) * 8;              // swizzled global k-segment (shorts)
  const unsigned short* gA1 = Xc + (size_t)(g0 + r1) * KC + sw;
  const unsigned short* gA2 = Xc + (size_t)(g0 + r1 + 32) * KC + sw;
  const unsigned short* gB1 = wb + (size_t)(c0 + r1) * KC + sw;
  const unsigned short* gB2 = wb + (size_t)(c0 + r1 + 32) * KC + sw;
  unsigned short* aD1 = As + wave * 512;
  unsigned short* aD2 = As + 2048 + wave * 512;
  unsigned short* bD1 = Bs + wave * 512;
  unsigned short* bD2 = Bs + 2048 + wave * 512;

  int slot0 = hi ^ (rsel & 7);        // kk=0
  int slot1 = (4 + hi) ^ (rsel & 7);  // kk=1

  for (int kt = 0; kt < KC / 64; ++kt) {
    gload_lds16(gA1, aD1);
    gload_lds16(gA2, aD2);
    gload_lds16(gB1, bD1);
    gload_lds16(gB2, bD2);
    gA1 += 64; gA2 += 64; gB1 += 64; gB2 += 64;
    __syncthreads();

    bf16x8 af[2][2], bfr[2][2];
    #pragma unroll
    for (int m = 0; m < 2; ++m) {
      int rowA = (wr * 32 + m * 16 + rsel) * 64;
      af[m][0] = *(const bf16x8*)(As + rowA + slot0 * 8);
      af[m][1] = *(const bf16x8*)(As + rowA + slot1 * 8);
    }
    #pragma unroll
    for (int n = 0; n < 2; ++n) {
      int rowB = (wc * 32 + n * 16 + rsel) * 64;
      bfr[n][0] = *(const bf16x8*)(Bs + rowB + slot0 * 8);
      bfr[n][1] = *(const bf16x8*)(Bs + rowB + slot1 * 8);
    }
    #pragma unroll
    for (int m = 0; m < 2; ++m)
      #pragma unroll
      for (int n = 0; n < 2; ++n) {
        acc[m][n] = __builtin_amdgcn_mfma_f32_16x16x32_bf16(af[m][0], bfr[n][0], acc[m][n], 0, 0, 0);
        acc[m][n] = __builtin_amdgcn_mfma_f32_16x16x32_bf16(af[m][1], bfr[n][1], acc[m][n], 0, 0, 0);
      }
    __syncthreads();
  }

  float bv[2];
  #pragma unroll
  for (int n = 0; n < 2; ++n) bv[n] = bias[c0 + wc * 32 + n * 16 + rsel];
  #pragma unroll
  for (int m = 0; m < 2; ++m)
    #pragma unroll
    for (int i = 0; i < 4; ++i) {
      int g = g0 + wr * 32 + m * 16 + hi * 4 + i;
      float* yr = y + (size_t)g * 1024;
      #pragma unroll
      for (int n = 0; n < 2; ++n)
        yr[c0 + wc * 32 + n * 16 + rsel] = acc[m][n][i] + bv[n];
    }
}

// ---------------------------------------------------------------------------
// GLU: xout[g][d] = y[g][d] * sigmoid(y[g][d+512]) + xres[g][d]
__global__ void k_glu(const float* __restrict__ y, const float* __restrict__ xres,
                      float* __restrict__ xout) {
  int idx = blockIdx.x * 256 + threadIdx.x;  // 2048*128
  int g = idx >> 7, d4 = (idx & 127) << 2;
  const float* yr = y + (size_t)g * 1024;
  float4 a = *(const float4*)(yr + d4);
  float4 bq = *(const float4*)(yr + 512 + d4);
  float4 xr = *(const float4*)(xres + (size_t)g * 512 + d4);
  float4 o;
  o.x = a.x / (1.f + expf(-bq.x)) + xr.x;
  o.y = a.y / (1.f + expf(-bq.y)) + xr.y;
  o.z = a.z / (1.f + expf(-bq.z)) + xr.z;
  o.w = a.w / (1.f + expf(-bq.w)) + xr.w;
  *(float4*)(xout + (size_t)g * 512 + d4) = o;
}

// Layer-2 GLU: writes bf16 x3 directly.
__global__ void k_glu_bf16(const float* __restrict__ y, const float* __restrict__ xres,
                           unsigned short* __restrict__ xout) {
  int idx = blockIdx.x * 256 + threadIdx.x;
  int g = idx >> 7, d4 = (idx & 127) << 2;
  const float* yr = y + (size_t)g * 1024;
  float4 a = *(const float4*)(yr + d4);
  float4 bq = *(const float4*)(yr + 512 + d4);
  float4 xr = *(const float4*)(xres + (size_t)g * 512 + d4);
  ushort4 o;
  o.x = f2bf(a.x / (1.f + expf(-bq.x)) + xr.x);
  o.y = f2bf(a.y / (1.f + expf(-bq.y)) + xr.y);
  o.z = f2bf(a.z / (1.f + expf(-bq.z)) + xr.z);
  o.w = f2bf(a.w / (1.f + expf(-bq.w)) + xr.w);
  *(ushort4*)(xout + (size_t)g * 512 + d4) = o;
}

// ---------------------------------------------------------------------------
// cbase[b,v] = b2[v] + ctx[b,:1024] . W2[v,:1024]  as bf16 MFMA.
// M=64, N=30000, K=1024. Block: 128 v-cols, 4 waves (N-split), K-step 64.
// A (ctx bf16) via gload_lds (pre-swizzled source); B (W2 fp32, coalesced
// 256B row-segments) reg-staged -> bf16 -> swizzled ds_write_b128.
__global__ __launch_bounds__(256) void k_cbase_mfma(
    const unsigned short* __restrict__ ctxb,  // [64][1024] bf16
    const float* __restrict__ W2,             // [30000][1536] fp32
    const float* __restrict__ b2, float* __restrict__ cbase) {
  __shared__ __align__(16) unsigned short As[64 * 64];    // 8 KB
  __shared__ __align__(16) unsigned short Bs[128 * 64];   // 16 KB
  int v0 = blockIdx.x * 128;
  int tid = threadIdx.x, lane = tid & 63, wave = tid >> 6;
  int rsel = lane & 15, hi = lane >> 4;
  int wc = wave;

  f32x4 acc[4][2];
  #pragma unroll
  for (int m = 0; m < 4; ++m)
    #pragma unroll
    for (int n = 0; n < 2; ++n) acc[m][n] = (f32x4){0.f, 0.f, 0.f, 0.f};

  // A staging: 512 chunks of 16B; thread q=tid and q=tid+256.
  int ra1 = tid >> 3, sa = tid & 7;
  int ra2 = ra1 + 32;
  const unsigned short* gA1 = ctxb + (size_t)ra1 * 1024 + (sa ^ (ra1 & 7)) * 8;
  const unsigned short* gA2 = ctxb + (size_t)ra2 * 1024 + (sa ^ (ra2 & 7)) * 8;
  unsigned short* aD1 = As + wave * 512;
  unsigned short* aD2 = As + 2048 + wave * 512;

  // B staging: 1024 8-float segments; thread handles p=0..3 (rows p*32 + tid>>3).
  const float* gB[4];
  int bofs[4];
  #pragma unroll
  for (int p = 0; p < 4; ++p) {
    int row = p * 32 + (tid >> 3);
    int seg = tid & 7;
    int vr = v0 + row; if (vr > V - 1) vr = V - 1;
    gB[p] = W2 + (size_t)vr * (E_ENC + D) + seg * 8;
    bofs[p] = row * 64 + (seg ^ (row & 7)) * 8;
  }

  for (int kt = 0; kt < 16; ++kt) {
    gload_lds16(gA1, aD1);
    gload_lds16(gA2, aD2);
    gA1 += 64; gA2 += 64;
    #pragma unroll
    for (int p = 0; p < 4; ++p) {
      float4 f0 = *(const float4*)(gB[p]);
      float4 f1 = *(const float4*)(gB[p] + 4);
      gB[p] += 64;
      bf16x8 o;
      o[0] = (short)f2bf(f0.x); o[1] = (short)f2bf(f0.y);
      o[2] = (short)f2bf(f0.z); o[3] = (short)f2bf(f0.w);
      o[4] = (short)f2bf(f1.x); o[5] = (short)f2bf(f1.y);
      o[6] = (short)f2bf(f1.z); o[7] = (short)f2bf(f1.w);
      *(bf16x8*)(Bs + bofs[p]) = o;
    }
    __syncthreads();

    bf16x8 af[4][2], bfr[2][2];
    #pragma unroll
    for (int m = 0; m < 4; ++m) {
      int rowA = (m * 16 + rsel) * 64;
      #pragma unroll
      for (int kk = 0; kk < 2; ++kk)
        af[m][kk] = *(const bf16x8*)(As + rowA + ((kk * 4 + hi) ^ (rsel & 7)) * 8);
    }
    #pragma unroll
    for (int n = 0; n < 2; ++n) {
      int rowB = (wc * 32 + n * 16 + rsel) * 64;
      #pragma unroll
      for (int kk = 0; kk < 2; ++kk)
        bfr[n][kk] = *(const bf16x8*)(Bs + rowB + ((kk * 4 + hi) ^ (rsel & 7)) * 8);
    }
    #pragma unroll
    for (int kk = 0; kk < 2; ++kk)
      #pragma unroll
      for (int m = 0; m < 4; ++m)
        #pragma unroll
        for (int n = 0; n < 2; ++n)
          acc[m][n] = __builtin_amdgcn_mfma_f32_16x16x32_bf16(af[m][kk], bfr[n][kk], acc[m][n], 0, 0, 0);
    __syncthreads();
  }

  #pragma unroll
  for (int n = 0; n < 2; ++n) {
    int v = v0 + wc * 32 + n * 16 + rsel;
    if (v >= V) continue;
    float bias = b2[v];
    #pragma unroll
    for (int m = 0; m < 4; ++m)
      #pragma unroll
      for (int i = 0; i < 4; ++i) {
        int b = m * 16 + hi * 4 + i;
        cbase[(size_t)b * V + v] = acc[m][n][i] + bias;
      }
  }
}

// ---------------------------------------------------------------------------
// W2 decode-half conversion: y[v][c] = bf16(W2[v][1024+c])
__global__ void k_cvt_w2d(const float* __restrict__ W2, unsigned short* __restrict__ y) {
  int i = blockIdx.x * 256 + threadIdx.x;   // 30000*128 groups of 4
  int row = i >> 7, c = (i & 127) << 2;
  float4 f = *(const float4*)(W2 + (size_t)row * (E_ENC + D) + E_ENC + c);
  ushort4 o;
  o.x = f2bf(f.x); o.y = f2bf(f.y); o.z = f2bf(f.z); o.w = f2bf(f.w);
  *(ushort4*)(y + (size_t)row * D + c) = o;
}

// ---------------------------------------------------------------------------
// logits[b,s,v] = cbase[b,v] + x3[b,s,:] . W2d[v,:]  (bf16 MFMA, m97 structure)
__global__ __launch_bounds__(256) void k_logits_mfma(
    const unsigned short* __restrict__ Ab,   // x3 bf16 [2048][512]
    const unsigned short* __restrict__ Bb,   // W2d bf16 [30000][512]
    const float* __restrict__ cbase, float* __restrict__ out) {
  __shared__ __align__(16) unsigned short As[128 * 32];
  __shared__ __align__(16) unsigned short Bs[128 * 32];
  int v0 = blockIdx.x * 128, g0 = blockIdx.y * 128;
  int tid = threadIdx.x;
  int lane = tid & 63, wave = tid >> 6;
  int wr = wave >> 1, wc = wave & 1;

  f32x4 acc[4][4];
  #pragma unroll
  for (int m = 0; m < 4; ++m)
    #pragma unroll
    for (int n = 0; n < 4; ++n) acc[m][n] = (f32x4){0.f, 0.f, 0.f, 0.f};

  int r1 = tid >> 2, s1 = tid & 3;
  unsigned short* aB1 = As + wave * 512;
  unsigned short* aB2 = As + wave * 512 + 2048;
  unsigned short* bB1 = Bs + wave * 512;
  unsigned short* bB2 = Bs + wave * 512 + 2048;
  int vrow1 = v0 + r1;      if (vrow1 > V - 1) vrow1 = V - 1;
  int vrow2 = v0 + r1 + 64; if (vrow2 > V - 1) vrow2 = V - 1;
  const unsigned short* gA1 = Ab + (size_t)(g0 + r1) * 512 + s1 * 8;
  const unsigned short* gA2 = Ab + (size_t)(g0 + r1 + 64) * 512 + s1 * 8;
  const unsigned short* gB1 = Bb + (size_t)vrow1 * 512 + s1 * 8;
  const unsigned short* gB2 = Bb + (size_t)vrow2 * 512 + s1 * 8;

  int rsel = lane & 15, hi = lane >> 4;

  for (int kt = 0; kt < 16; ++kt) {
    gload_lds16(gA1, aB1);
    gload_lds16(gA2, aB2);
    gload_lds16(gB1, bB1);
    gload_lds16(gB2, bB2);
    gA1 += 32; gA2 += 32; gB1 += 32; gB2 += 32;
    __syncthreads();

    bf16x8 af[4], bfr[4];
    #pragma unroll
    for (int m = 0; m < 4; ++m)
      af[m] = *(const bf16x8*)(As + (wr * 64 + m * 16 + rsel) * 32 + hi * 8);
    #pragma unroll
    for (int n = 0; n < 4; ++n)
      bfr[n] = *(const bf16x8*)(Bs + (wc * 64 + n * 16 + rsel) * 32 + hi * 8);
    #pragma unroll
    for (int m = 0; m < 4; ++m)
      #pragma unroll
      for (int n = 0; n < 4; ++n)
        acc[m][n] = __builtin_amdgcn_mfma_f32_16x16x32_bf16(af[m], bfr[n], acc[m][n], 0, 0, 0);
    __syncthreads();
  }

  #pragma unroll
  for (int m = 0; m < 4; ++m) {
    #pragma unroll
    for (int i = 0; i < 4; ++i) {
      int g = g0 + wr * 64 + m * 16 + hi * 4 + i;
      int b = g >> 5, lt = g & 31;
      if (lt >= S) continue;
      size_t orow = ((size_t)b * S + lt) * V;
      const float* cb = cbase + (size_t)b * V;
      #pragma unroll
      for (int n = 0; n < 4; ++n) {
        int v = v0 + wc * 64 + n * 16 + rsel;
        if (v < V) out[orow + v] = acc[m][n][i] + cb[v];
      }
    }
  }
}

// ---------------------------------------------------------------------------
extern "C" void kernel_launch(void* const* d_in, const int* in_sizes, int n_in,
                              void* d_out, int out_size, void* d_ws, size_t ws_size,
                              hipStream_t stream) {
  const float* features = (const float*)d_in[0];
  const int*   captions = (const int*)d_in[1];
  const float* embed_W  = (const float*)d_in[3];
  const float* W1   = (const float*)d_in[4];
  const float* b1   = (const float*)d_in[5];
  const float* cw1  = (const float*)d_in[6];
  const float* cb1  = (const float*)d_in[7];
  const float* cw2  = (const float*)d_in[8];
  const float* cb2  = (const float*)d_in[9];
  const float* Wenc = (const float*)d_in[10];
  const float* benc = (const float*)d_in[11];
  const float* Wp   = (const float*)d_in[14];
  const float* W2   = (const float*)d_in[16];
  const float* b2   = (const float*)d_in[17];
  float* out = (float*)d_out;

  float* ws = (float*)d_ws;
  float* wv       = ws;                 // 1024
  float* c0       = ws + 1024;          // 16
  float* enc_mean = ws + 1040;          // 65536
  unsigned short* ctxb = (unsigned short*)(ws + 66576);  // 65536 bf16 (32768 fl slot)
  float* base1    = ws + 132112;        // 32768
  float* xA       = ws + 164880;        // 1048576 (x1; dead after GLU1)
  float* xB       = ws + 1213456;       // 1048576 (x2)
  float* y        = ws + 2262032;       // 2097152 (conv GEMM out; cbase aliases after)
  float* cbase    = y;                  // 1920000 <= 2097152, y dead by then
  unsigned short* x3b  = (unsigned short*)xA;             // 1048576 bf16 (xA dead)
  unsigned short* Xc   = (unsigned short*)(ws + 4359184); // 7340032 bf16
  unsigned short* wbuf = (unsigned short*)(ws + 8029200); // 3670016 bf16
  unsigned short* W2d  = (unsigned short*)(ws + 9864208); // 15360000 bf16
  // end: 17,544,208 floats = 70.2 MB

  hipLaunchKernelGGL(k_cvt_w2d,  dim3(15000),   dim3(256), 0, stream, W2, W2d);
  hipLaunchKernelGGL(k_wv,       dim3(4),       dim3(256), 0, stream, Wenc, Wp, benc, wv, c0);
  hipLaunchKernelGGL(k_mean_ctx, dim3(B),       dim3(256), 0, stream, features, wv, c0, enc_mean, ctxb);
  hipLaunchKernelGGL(k_base1,    dim3(B),       dim3(256), 0, stream, enc_mean, W1, b1, base1);
  hipLaunchKernelGGL(k_x1,       dim3(B),       dim3(256), 0, stream, embed_W, captions, W1, base1, xA);

  // conv layer 1
  hipLaunchKernelGGL(k_cvt_wconv, dim3(1024),   dim3(256), 0, stream, cw1, wbuf);
  hipLaunchKernelGGL(k_im2col,    dim3(2048),   dim3(256), 0, stream, xA, Xc);
  hipLaunchKernelGGL(k_conv_mfma, dim3(16, 32), dim3(256), 0, stream, Xc, wbuf, cb1, y);
  hipLaunchKernelGGL(k_glu,       dim3(1024),   dim3(256), 0, stream, y, xA, xB);

  // conv layer 2
  hipLaunchKernelGGL(k_cvt_wconv, dim3(1024),   dim3(256), 0, stream, cw2, wbuf);
  hipLaunchKernelGGL(k_im2col,    dim3(2048),   dim3(256), 0, stream, xB, Xc);
  hipLaunchKernelGGL(k_conv_mfma, dim3(16, 32), dim3(256), 0, stream, Xc, wbuf, cb2, y);
  hipLaunchKernelGGL(k_glu_bf16,  dim3(1024),   dim3(256), 0, stream, y, xB, x3b);

  hipLaunchKernelGGL(k_cbase_mfma, dim3(235),   dim3(256), 0, stream, ctxb, W2, b2, cbase);
  hipLaunchKernelGGL(k_logits_mfma, dim3(235, 16), dim3(256), 0, stream, x3b, W2d, cbase, out);
}

// Round 5
// 467.149 us; speedup vs baseline: 5.6036x; 1.3908x over previous
//
#include <hip/hip_runtime.h>
#include <hip/hip_bf16.h>
#include <math.h>

// Sizes (fixed by the problem)
#define B 64
#define T 64
#define E_ENC 1024
#define EMB 512
#define D 512
#define L 32
#define S 31
#define A 512
#define V 30000
#define KSZ 7
#define KC (D * KSZ)   // 3584 = conv GEMM K

typedef __attribute__((ext_vector_type(8))) short bf16x8;
typedef __attribute__((ext_vector_type(4))) float f32x4;

__device__ __forceinline__ unsigned short f2bf(float f) {
  union { float f; unsigned int u; } x; x.f = f;
  unsigned int r = (x.u + 0x7fffu + ((x.u >> 16) & 1u)) >> 16;
  return (unsigned short)r;
}

__device__ __forceinline__ void gload_lds16(const void* g, void* l) {
  __builtin_amdgcn_global_load_lds(
      (const __attribute__((address_space(1))) unsigned int*)g,
      (__attribute__((address_space(3))) unsigned int*)l, 16, 0, 0);
}

// ---------------------------------------------------------------------------
// wv[e] = sum_a Wp[a]*Wenc[a,e];  c0 = sum_a benc[a]*Wp[a]
__global__ void k_wv(const float* __restrict__ Wenc, const float* __restrict__ Wp,
                     const float* __restrict__ benc, float* __restrict__ wv,
                     float* __restrict__ c0) {
  __shared__ float red[256];
  int e = blockIdx.x * 256 + threadIdx.x;
  float s = 0.f;
  for (int a = 0; a < A; ++a) s += Wp[a] * Wenc[(size_t)a * E_ENC + e];
  wv[e] = s;
  if (blockIdx.x == 0) {
    int t = threadIdx.x;
    float v = Wp[t] * benc[t] + Wp[t + 256] * benc[t + 256];
    red[t] = v;
    __syncthreads();
    for (int off = 128; off > 0; off >>= 1) {
      if (t < off) red[t] += red[t + off];
      __syncthreads();
    }
    if (t == 0) c0[0] = red[0];
  }
}

// ---------------------------------------------------------------------------
// Per-b: enc_mean[b,:], fscore -> softmax over t -> ctx (bf16)
__global__ void k_mean_ctx(const float* __restrict__ features, const float* __restrict__ wv,
                           const float* __restrict__ c0, float* __restrict__ enc_mean,
                           unsigned short* __restrict__ ctxb) {
  int b = blockIdx.x, tid = threadIdx.x;
  const float* fb = features + (size_t)b * T * E_ENC;
  __shared__ float s_attw[T];

  float m0 = 0, m1 = 0, m2 = 0, m3 = 0;
  for (int t = 0; t < T; ++t) {
    const float* r = fb + t * E_ENC;
    m0 += r[tid]; m1 += r[tid + 256]; m2 += r[tid + 512]; m3 += r[tid + 768];
  }
  size_t eb = (size_t)b * E_ENC;
  enc_mean[eb + tid]       = m0 * (1.f / 64.f);
  enc_mean[eb + tid + 256] = m1 * (1.f / 64.f);
  enc_mean[eb + tid + 512] = m2 * (1.f / 64.f);
  enc_mean[eb + tid + 768] = m3 * (1.f / 64.f);

  {
    int t = tid >> 2, part = tid & 3;
    const float* r = fb + t * E_ENC + part * 256;
    const float* wp = wv + part * 256;
    float s = 0.f;
    for (int e = 0; e < 256; e += 4) {
      float4 f4 = *(const float4*)(r + e);
      float4 w4 = *(const float4*)(wp + e);
      s += f4.x * w4.x + f4.y * w4.y + f4.z * w4.z + f4.w * w4.w;
    }
    s += __shfl_xor(s, 1);
    s += __shfl_xor(s, 2);
    if (part == 0) s_attw[t] = s + c0[0];
  }
  __syncthreads();
  if (tid < 64) {
    float v = s_attw[tid];
    float mx = v;
    #pragma unroll
    for (int off = 32; off > 0; off >>= 1) mx = fmaxf(mx, __shfl_xor(mx, off));
    float e = expf(v - mx);
    float sm = e;
    #pragma unroll
    for (int off = 32; off > 0; off >>= 1) sm += __shfl_xor(sm, off);
    s_attw[tid] = e / sm;
  }
  __syncthreads();
  float ca = 0, cb = 0, cc = 0, cd = 0;
  for (int t = 0; t < T; ++t) {
    float w = s_attw[t];
    const float* r = fb + t * E_ENC;
    ca += w * r[tid]; cb += w * r[tid + 256]; cc += w * r[tid + 512]; cd += w * r[tid + 768];
  }
  ctxb[eb + tid]       = f2bf(ca);
  ctxb[eb + tid + 256] = f2bf(cb);
  ctxb[eb + tid + 512] = f2bf(cc);
  ctxb[eb + tid + 768] = f2bf(cd);
}

// ---------------------------------------------------------------------------
// base1[b,d] = b1[d] + enc_mean[b,:1024] . W1[d,:1024]
__global__ void k_base1(const float* __restrict__ enc_mean, const float* __restrict__ W1,
                        const float* __restrict__ b1, float* __restrict__ base1) {
  __shared__ float em[E_ENC];
  int b = blockIdx.x, tid = threadIdx.x;
  for (int i = tid; i < E_ENC; i += 256) em[i] = enc_mean[(size_t)b * E_ENC + i];
  __syncthreads();
  for (int d = tid; d < D; d += 256) {
    const float* w = W1 + (size_t)d * (E_ENC + EMB);
    float acc = 0.f;
    for (int e = 0; e < E_ENC; e += 4) {
      float4 w4 = *(const float4*)(w + e);
      acc += w4.x * em[e] + w4.y * em[e + 1] + w4.z * em[e + 2] + w4.w * em[e + 3];
    }
    base1[b * D + d] = acc + b1[d];
  }
}

// ---------------------------------------------------------------------------
// Gather embedding rows per caption token -> bf16 Xe[2048][512]
__global__ void k_gather_emb(const float* __restrict__ embed_W,
                             const int* __restrict__ captions,
                             unsigned short* __restrict__ Xe) {
  int g = blockIdx.x, tid = threadIdx.x;
  int cap = captions[g];
  const float* src = embed_W + (size_t)cap * EMB;
  float2 v = *(const float2*)(src + tid * 2);
  unsigned int pk = (unsigned int)f2bf(v.x) | ((unsigned int)f2bf(v.y) << 16);
  *(unsigned int*)(Xe + (size_t)g * EMB + tid * 2) = pk;
}

// W1 decode-half conversion: w1db[d][c] = bf16(W1[d][1024+c])
__global__ void k_cvt_w1d(const float* __restrict__ W1, unsigned short* __restrict__ w1db) {
  int d = blockIdx.x, tid = threadIdx.x;
  float2 v = *(const float2*)(W1 + (size_t)d * (E_ENC + EMB) + E_ENC + tid * 2);
  unsigned int pk = (unsigned int)f2bf(v.x) | ((unsigned int)f2bf(v.y) << 16);
  *(unsigned int*)(w1db + (size_t)d * EMB + tid * 2) = pk;
}

// ---------------------------------------------------------------------------
// x1 GEMM: x1[g][d] = base1[g>>5][d] + Xe[g,:] . w1db[d,:]   M=2048,N=512,K=512
// Same structure as k_conv_mfma (64x64 tile, BK=64, XOR slot swizzle).
__global__ __launch_bounds__(256) void k_x1_mfma(
    const unsigned short* __restrict__ Xe, const unsigned short* __restrict__ w1db,
    const float* __restrict__ base1, float* __restrict__ x1) {
  __shared__ __align__(16) unsigned short As[64 * 64];  // 8 KB
  __shared__ __align__(16) unsigned short Bs[64 * 64];  // 8 KB
  int c0 = blockIdx.x * 64, g0 = blockIdx.y * 64;
  int tid = threadIdx.x, lane = tid & 63, wave = tid >> 6;
  int wr = wave >> 1, wc = wave & 1;
  int rsel = lane & 15, hi = lane >> 4;

  f32x4 acc[2][2];
  #pragma unroll
  for (int m = 0; m < 2; ++m)
    #pragma unroll
    for (int n = 0; n < 2; ++n) acc[m][n] = (f32x4){0.f, 0.f, 0.f, 0.f};

  int r1 = tid >> 3, s1 = tid & 7;
  int sw = (s1 ^ (r1 & 7)) * 8;
  const unsigned short* gA1 = Xe + (size_t)(g0 + r1) * EMB + sw;
  const unsigned short* gA2 = Xe + (size_t)(g0 + r1 + 32) * EMB + sw;
  const unsigned short* gB1 = w1db + (size_t)(c0 + r1) * EMB + sw;
  const unsigned short* gB2 = w1db + (size_t)(c0 + r1 + 32) * EMB + sw;
  unsigned short* aD1 = As + wave * 512;
  unsigned short* aD2 = As + 2048 + wave * 512;
  unsigned short* bD1 = Bs + wave * 512;
  unsigned short* bD2 = Bs + 2048 + wave * 512;

  int slot0 = hi ^ (rsel & 7);
  int slot1 = (4 + hi) ^ (rsel & 7);

  for (int kt = 0; kt < EMB / 64; ++kt) {
    gload_lds16(gA1, aD1);
    gload_lds16(gA2, aD2);
    gload_lds16(gB1, bD1);
    gload_lds16(gB2, bD2);
    gA1 += 64; gA2 += 64; gB1 += 64; gB2 += 64;
    __syncthreads();

    bf16x8 af[2][2], bfr[2][2];
    #pragma unroll
    for (int m = 0; m < 2; ++m) {
      int rowA = (wr * 32 + m * 16 + rsel) * 64;
      af[m][0] = *(const bf16x8*)(As + rowA + slot0 * 8);
      af[m][1] = *(const bf16x8*)(As + rowA + slot1 * 8);
    }
    #pragma unroll
    for (int n = 0; n < 2; ++n) {
      int rowB = (wc * 32 + n * 16 + rsel) * 64;
      bfr[n][0] = *(const bf16x8*)(Bs + rowB + slot0 * 8);
      bfr[n][1] = *(const bf16x8*)(Bs + rowB + slot1 * 8);
    }
    #pragma unroll
    for (int m = 0; m < 2; ++m)
      #pragma unroll
      for (int n = 0; n < 2; ++n) {
        acc[m][n] = __builtin_amdgcn_mfma_f32_16x16x32_bf16(af[m][0], bfr[n][0], acc[m][n], 0, 0, 0);
        acc[m][n] = __builtin_amdgcn_mfma_f32_16x16x32_bf16(af[m][1], bfr[n][1], acc[m][n], 0, 0, 0);
      }
    __syncthreads();
  }

  #pragma unroll
  for (int m = 0; m < 2; ++m)
    #pragma unroll
    for (int i = 0; i < 4; ++i) {
      int g = g0 + wr * 32 + m * 16 + hi * 4 + i;
      const float* br = base1 + (size_t)(g >> 5) * D;
      float* xr = x1 + (size_t)g * D;
      #pragma unroll
      for (int n = 0; n < 2; ++n) {
        int c = c0 + wc * 32 + n * 16 + rsel;
        xr[c] = acc[m][n][i] + br[c];
      }
    }
}

// ---------------------------------------------------------------------------
// im2col: Xc[g][k*512+dp] = (l+k-6 >= 0) ? x[b][l+k-6][dp] : 0   (bf16)
__global__ void k_im2col(const float* __restrict__ x, unsigned short* __restrict__ Xc) {
  int g = blockIdx.x, tid = threadIdx.x;
  int b = g >> 5, l = g & 31;
  unsigned short* row = Xc + (size_t)g * KC;
  const float* xb = x + (size_t)b * L * D;
  int d = tid * 2;
  #pragma unroll
  for (int k = 0; k < KSZ; ++k) {
    int lp = l + k - 6;
    unsigned int pk = 0;
    if (lp >= 0) {
      float2 v = *(const float2*)(xb + (size_t)lp * D + d);
      pk = (unsigned int)f2bf(v.x) | ((unsigned int)f2bf(v.y) << 16);
    }
    *(unsigned int*)(row + k * 512 + d) = pk;
  }
}

// ---------------------------------------------------------------------------
// conv weight reorder+convert: wb[c][k*512+dp] = bf16(w[c][dp*7+k])
__global__ void k_cvt_wconv(const float* __restrict__ w, unsigned short* __restrict__ wb) {
  __shared__ float row[KC];  // 14 KiB
  int c = blockIdx.x, tid = threadIdx.x;
  const float* wr = w + (size_t)c * KC;
  for (int i = tid; i < KC; i += 256) row[i] = wr[i];
  __syncthreads();
  unsigned short* ob = wb + (size_t)c * KC;
  int dp = tid * 2;
  #pragma unroll
  for (int k = 0; k < KSZ; ++k) {
    unsigned int pk = (unsigned int)f2bf(row[dp * 7 + k]) |
                      ((unsigned int)f2bf(row[(dp + 1) * 7 + k]) << 16);
    *(unsigned int*)(ob + k * 512 + dp) = pk;
  }
}

// ---------------------------------------------------------------------------
// Conv GEMM: y[g][c] = bias[c] + Xc[g,:] . wb[c,:]   M=2048, N=1024, K=3584
__global__ __launch_bounds__(256) void k_conv_mfma(
    const unsigned short* __restrict__ Xc, const unsigned short* __restrict__ wb,
    const float* __restrict__ bias, float* __restrict__ y) {
  __shared__ __align__(16) unsigned short As[64 * 64];  // 8 KB
  __shared__ __align__(16) unsigned short Bs[64 * 64];  // 8 KB
  int c0 = blockIdx.x * 64, g0 = blockIdx.y * 64;
  int tid = threadIdx.x, lane = tid & 63, wave = tid >> 6;
  int wr = wave >> 1, wc = wave & 1;
  int rsel = lane & 15, hi = lane >> 4;

  f32x4 acc[2][2];
  #pragma unroll
  for (int m = 0; m < 2; ++m)
    #pragma unroll
    for (int n = 0; n < 2; ++n) acc[m][n] = (f32x4){0.f, 0.f, 0.f, 0.f};

  int r1 = tid >> 3, s1 = tid & 7;
  int sw = (s1 ^ (r1 & 7)) * 8;              // swizzled global k-segment (shorts)
  const unsigned short* gA1 = Xc + (size_t)(g0 + r1) * KC + sw;
  const unsigned short* gA2 = Xc + (size_t)(g0 + r1 + 32) * KC + sw;
  const unsigned short* gB1 = wb + (size_t)(c0 + r1) * KC + sw;
  const unsigned short* gB2 = wb + (size_t)(c0 + r1 + 32) * KC + sw;
  unsigned short* aD1 = As + wave * 512;
  unsigned short* aD2 = As + 2048 + wave * 512;
  unsigned short* bD1 = Bs + wave * 512;
  unsigned short* bD2 = Bs + 2048 + wave * 512;

  int slot0 = hi ^ (rsel & 7);        // kk=0
  int slot1 = (4 + hi) ^ (rsel & 7);  // kk=1

  for (int kt = 0; kt < KC / 64; ++kt) {
    gload_lds16(gA1, aD1);
    gload_lds16(gA2, aD2);
    gload_lds16(gB1, bD1);
    gload_lds16(gB2, bD2);
    gA1 += 64; gA2 += 64; gB1 += 64; gB2 += 64;
    __syncthreads();

    bf16x8 af[2][2], bfr[2][2];
    #pragma unroll
    for (int m = 0; m < 2; ++m) {
      int rowA = (wr * 32 + m * 16 + rsel) * 64;
      af[m][0] = *(const bf16x8*)(As + rowA + slot0 * 8);
      af[m][1] = *(const bf16x8*)(As + rowA + slot1 * 8);
    }
    #pragma unroll
    for (int n = 0; n < 2; ++n) {
      int rowB = (wc * 32 + n * 16 + rsel) * 64;
      bfr[n][0] = *(const bf16x8*)(Bs + rowB + slot0 * 8);
      bfr[n][1] = *(const bf16x8*)(Bs + rowB + slot1 * 8);
    }
    #pragma unroll
    for (int m = 0; m < 2; ++m)
      #pragma unroll
      for (int n = 0; n < 2; ++n) {
        acc[m][n] = __builtin_amdgcn_mfma_f32_16x16x32_bf16(af[m][0], bfr[n][0], acc[m][n], 0, 0, 0);
        acc[m][n] = __builtin_amdgcn_mfma_f32_16x16x32_bf16(af[m][1], bfr[n][1], acc[m][n], 0, 0, 0);
      }
    __syncthreads();
  }

  float bv[2];
  #pragma unroll
  for (int n = 0; n < 2; ++n) bv[n] = bias[c0 + wc * 32 + n * 16 + rsel];
  #pragma unroll
  for (int m = 0; m < 2; ++m)
    #pragma unroll
    for (int i = 0; i < 4; ++i) {
      int g = g0 + wr * 32 + m * 16 + hi * 4 + i;
      float* yr = y + (size_t)g * 1024;
      #pragma unroll
      for (int n = 0; n < 2; ++n)
        yr[c0 + wc * 32 + n * 16 + rsel] = acc[m][n][i] + bv[n];
    }
}

// ---------------------------------------------------------------------------
// GLU: xout[g][d] = y[g][d] * sigmoid(y[g][d+512]) + xres[g][d]
__global__ void k_glu(const float* __restrict__ y, const float* __restrict__ xres,
                      float* __restrict__ xout) {
  int idx = blockIdx.x * 256 + threadIdx.x;  // 2048*128
  int g = idx >> 7, d4 = (idx & 127) << 2;
  const float* yr = y + (size_t)g * 1024;
  float4 a = *(const float4*)(yr + d4);
  float4 bq = *(const float4*)(yr + 512 + d4);
  float4 xr = *(const float4*)(xres + (size_t)g * 512 + d4);
  float4 o;
  o.x = a.x / (1.f + expf(-bq.x)) + xr.x;
  o.y = a.y / (1.f + expf(-bq.y)) + xr.y;
  o.z = a.z / (1.f + expf(-bq.z)) + xr.z;
  o.w = a.w / (1.f + expf(-bq.w)) + xr.w;
  *(float4*)(xout + (size_t)g * 512 + d4) = o;
}

// Layer-2 GLU: writes bf16 x3 directly.
__global__ void k_glu_bf16(const float* __restrict__ y, const float* __restrict__ xres,
                           unsigned short* __restrict__ xout) {
  int idx = blockIdx.x * 256 + threadIdx.x;
  int g = idx >> 7, d4 = (idx & 127) << 2;
  const float* yr = y + (size_t)g * 1024;
  float4 a = *(const float4*)(yr + d4);
  float4 bq = *(const float4*)(yr + 512 + d4);
  float4 xr = *(const float4*)(xres + (size_t)g * 512 + d4);
  ushort4 o;
  o.x = f2bf(a.x / (1.f + expf(-bq.x)) + xr.x);
  o.y = f2bf(a.y / (1.f + expf(-bq.y)) + xr.y);
  o.z = f2bf(a.z / (1.f + expf(-bq.z)) + xr.z);
  o.w = f2bf(a.w / (1.f + expf(-bq.w)) + xr.w);
  *(ushort4*)(xout + (size_t)g * 512 + d4) = o;
}

// ---------------------------------------------------------------------------
// cbase[b,v] = b2[v] + ctx[b,:1024] . W2[v,:1024]  as bf16 MFMA.
__global__ __launch_bounds__(256) void k_cbase_mfma(
    const unsigned short* __restrict__ ctxb,  // [64][1024] bf16
    const float* __restrict__ W2,             // [30000][1536] fp32
    const float* __restrict__ b2, float* __restrict__ cbase) {
  __shared__ __align__(16) unsigned short As[64 * 64];    // 8 KB
  __shared__ __align__(16) unsigned short Bs[128 * 64];   // 16 KB
  int v0 = blockIdx.x * 128;
  int tid = threadIdx.x, lane = tid & 63, wave = tid >> 6;
  int rsel = lane & 15, hi = lane >> 4;
  int wc = wave;

  f32x4 acc[4][2];
  #pragma unroll
  for (int m = 0; m < 4; ++m)
    #pragma unroll
    for (int n = 0; n < 2; ++n) acc[m][n] = (f32x4){0.f, 0.f, 0.f, 0.f};

  int ra1 = tid >> 3, sa = tid & 7;
  int ra2 = ra1 + 32;
  const unsigned short* gA1 = ctxb + (size_t)ra1 * 1024 + (sa ^ (ra1 & 7)) * 8;
  const unsigned short* gA2 = ctxb + (size_t)ra2 * 1024 + (sa ^ (ra2 & 7)) * 8;
  unsigned short* aD1 = As + wave * 512;
  unsigned short* aD2 = As + 2048 + wave * 512;

  const float* gB[4];
  int bofs[4];
  #pragma unroll
  for (int p = 0; p < 4; ++p) {
    int row = p * 32 + (tid >> 3);
    int seg = tid & 7;
    int vr = v0 + row; if (vr > V - 1) vr = V - 1;
    gB[p] = W2 + (size_t)vr * (E_ENC + D) + seg * 8;
    bofs[p] = row * 64 + (seg ^ (row & 7)) * 8;
  }

  for (int kt = 0; kt < 16; ++kt) {
    gload_lds16(gA1, aD1);
    gload_lds16(gA2, aD2);
    gA1 += 64; gA2 += 64;
    #pragma unroll
    for (int p = 0; p < 4; ++p) {
      float4 f0 = *(const float4*)(gB[p]);
      float4 f1 = *(const float4*)(gB[p] + 4);
      gB[p] += 64;
      bf16x8 o;
      o[0] = (short)f2bf(f0.x); o[1] = (short)f2bf(f0.y);
      o[2] = (short)f2bf(f0.z); o[3] = (short)f2bf(f0.w);
      o[4] = (short)f2bf(f1.x); o[5] = (short)f2bf(f1.y);
      o[6] = (short)f2bf(f1.z); o[7] = (short)f2bf(f1.w);
      *(bf16x8*)(Bs + bofs[p]) = o;
    }
    __syncthreads();

    bf16x8 af[4][2], bfr[2][2];
    #pragma unroll
    for (int m = 0; m < 4; ++m) {
      int rowA = (m * 16 + rsel) * 64;
      #pragma unroll
      for (int kk = 0; kk < 2; ++kk)
        af[m][kk] = *(const bf16x8*)(As + rowA + ((kk * 4 + hi) ^ (rsel & 7)) * 8);
    }
    #pragma unroll
    for (int n = 0; n < 2; ++n) {
      int rowB = (wc * 32 + n * 16 + rsel) * 64;
      #pragma unroll
      for (int kk = 0; kk < 2; ++kk)
        bfr[n][kk] = *(const bf16x8*)(Bs + rowB + ((kk * 4 + hi) ^ (rsel & 7)) * 8);
    }
    #pragma unroll
    for (int kk = 0; kk < 2; ++kk)
      #pragma unroll
      for (int m = 0; m < 4; ++m)
        #pragma unroll
        for (int n = 0; n < 2; ++n)
          acc[m][n] = __builtin_amdgcn_mfma_f32_16x16x32_bf16(af[m][kk], bfr[n][kk], acc[m][n], 0, 0, 0);
    __syncthreads();
  }

  #pragma unroll
  for (int n = 0; n < 2; ++n) {
    int v = v0 + wc * 32 + n * 16 + rsel;
    if (v >= V) continue;
    float bias = b2[v];
    #pragma unroll
    for (int m = 0; m < 4; ++m)
      #pragma unroll
      for (int i = 0; i < 4; ++i) {
        int b = m * 16 + hi * 4 + i;
        cbase[(size_t)b * V + v] = acc[m][n][i] + bias;
      }
  }
}

// ---------------------------------------------------------------------------
// W2 decode-half conversion: y[v][c] = bf16(W2[v][1024+c])
__global__ void k_cvt_w2d(const float* __restrict__ W2, unsigned short* __restrict__ y) {
  int i = blockIdx.x * 256 + threadIdx.x;   // 30000*128 groups of 4
  int row = i >> 7, c = (i & 127) << 2;
  float4 f = *(const float4*)(W2 + (size_t)row * (E_ENC + D) + E_ENC + c);
  ushort4 o;
  o.x = f2bf(f.x); o.y = f2bf(f.y); o.z = f2bf(f.z); o.w = f2bf(f.w);
  *(ushort4*)(y + (size_t)row * D + c) = o;
}

// ---------------------------------------------------------------------------
// logits[b,s,v] = cbase[b,v] + x3[b,s,:] . W2d[v,:]  (bf16 MFMA, m97 structure)
__global__ __launch_bounds__(256) void k_logits_mfma(
    const unsigned short* __restrict__ Ab,   // x3 bf16 [2048][512]
    const unsigned short* __restrict__ Bb,   // W2d bf16 [30000][512]
    const float* __restrict__ cbase, float* __restrict__ out) {
  __shared__ __align__(16) unsigned short As[128 * 32];
  __shared__ __align__(16) unsigned short Bs[128 * 32];
  int v0 = blockIdx.x * 128, g0 = blockIdx.y * 128;
  int tid = threadIdx.x;
  int lane = tid & 63, wave = tid >> 6;
  int wr = wave >> 1, wc = wave & 1;

  f32x4 acc[4][4];
  #pragma unroll
  for (int m = 0; m < 4; ++m)
    #pragma unroll
    for (int n = 0; n < 4; ++n) acc[m][n] = (f32x4){0.f, 0.f, 0.f, 0.f};

  int r1 = tid >> 2, s1 = tid & 3;
  unsigned short* aB1 = As + wave * 512;
  unsigned short* aB2 = As + wave * 512 + 2048;
  unsigned short* bB1 = Bs + wave * 512;
  unsigned short* bB2 = Bs + wave * 512 + 2048;
  int vrow1 = v0 + r1;      if (vrow1 > V - 1) vrow1 = V - 1;
  int vrow2 = v0 + r1 + 64; if (vrow2 > V - 1) vrow2 = V - 1;
  const unsigned short* gA1 = Ab + (size_t)(g0 + r1) * 512 + s1 * 8;
  const unsigned short* gA2 = Ab + (size_t)(g0 + r1 + 64) * 512 + s1 * 8;
  const unsigned short* gB1 = Bb + (size_t)vrow1 * 512 + s1 * 8;
  const unsigned short* gB2 = Bb + (size_t)vrow2 * 512 + s1 * 8;

  int rsel = lane & 15, hi = lane >> 4;

  for (int kt = 0; kt < 16; ++kt) {
    gload_lds16(gA1, aB1);
    gload_lds16(gA2, aB2);
    gload_lds16(gB1, bB1);
    gload_lds16(gB2, bB2);
    gA1 += 32; gA2 += 32; gB1 += 32; gB2 += 32;
    __syncthreads();

    bf16x8 af[4], bfr[4];
    #pragma unroll
    for (int m = 0; m < 4; ++m)
      af[m] = *(const bf16x8*)(As + (wr * 64 + m * 16 + rsel) * 32 + hi * 8);
    #pragma unroll
    for (int n = 0; n < 4; ++n)
      bfr[n] = *(const bf16x8*)(Bs + (wc * 64 + n * 16 + rsel) * 32 + hi * 8);
    #pragma unroll
    for (int m = 0; m < 4; ++m)
      #pragma unroll
      for (int n = 0; n < 4; ++n)
        acc[m][n] = __builtin_amdgcn_mfma_f32_16x16x32_bf16(af[m], bfr[n], acc[m][n], 0, 0, 0);
    __syncthreads();
  }

  #pragma unroll
  for (int m = 0; m < 4; ++m) {
    #pragma unroll
    for (int i = 0; i < 4; ++i) {
      int g = g0 + wr * 64 + m * 16 + hi * 4 + i;
      int b = g >> 5, lt = g & 31;
      if (lt >= S) continue;
      size_t orow = ((size_t)b * S + lt) * V;
      const float* cb = cbase + (size_t)b * V;
      #pragma unroll
      for (int n = 0; n < 4; ++n) {
        int v = v0 + wc * 64 + n * 16 + rsel;
        if (v < V) out[orow + v] = acc[m][n][i] + cb[v];
      }
    }
  }
}

// ---------------------------------------------------------------------------
extern "C" void kernel_launch(void* const* d_in, const int* in_sizes, int n_in,
                              void* d_out, int out_size, void* d_ws, size_t ws_size,
                              hipStream_t stream) {
  const float* features = (const float*)d_in[0];
  const int*   captions = (const int*)d_in[1];
  const float* embed_W  = (const float*)d_in[3];
  const float* W1   = (const float*)d_in[4];
  const float* b1   = (const float*)d_in[5];
  const float* cw1  = (const float*)d_in[6];
  const float* cb1  = (const float*)d_in[7];
  const float* cw2  = (const float*)d_in[8];
  const float* cb2  = (const float*)d_in[9];
  const float* Wenc = (const float*)d_in[10];
  const float* benc = (const float*)d_in[11];
  const float* Wp   = (const float*)d_in[14];
  const float* W2   = (const float*)d_in[16];
  const float* b2   = (const float*)d_in[17];
  float* out = (float*)d_out;

  float* ws = (float*)d_ws;
  float* wv       = ws;                 // 1024
  float* c0       = ws + 1024;          // 16
  float* enc_mean = ws + 1040;          // 65536
  unsigned short* ctxb = (unsigned short*)(ws + 66576);  // 65536 bf16
  float* base1    = ws + 132112;        // 32768
  float* xA       = ws + 164880;        // 1048576 (x1; dead after GLU1)
  float* xB       = ws + 1213456;       // 1048576 (x2)
  float* y        = ws + 2262032;       // 2097152 (conv GEMM out; cbase aliases)
  float* cbase    = y;                  // 1920000 <= 2097152
  unsigned short* x3b  = (unsigned short*)xA;             // 1048576 bf16 (xA dead)
  unsigned short* Xc   = (unsigned short*)(ws + 4359184); // 7340032 bf16
  unsigned short* wbuf = (unsigned short*)(ws + 8029200); // 3670016 bf16
  unsigned short* W2d  = (unsigned short*)(ws + 9864208); // 15360000 bf16
  // Xe / w1db live inside the Xc region (free until im2col layer 1)
  unsigned short* Xe   = Xc;                 // 1048576 bf16
  unsigned short* w1db = Xc + 1048576;       // 262144 bf16
  // end: 17,544,208 floats = 70.2 MB (unchanged)

  hipLaunchKernelGGL(k_cvt_w2d,  dim3(15000),   dim3(256), 0, stream, W2, W2d);
  hipLaunchKernelGGL(k_wv,       dim3(4),       dim3(256), 0, stream, Wenc, Wp, benc, wv, c0);
  hipLaunchKernelGGL(k_mean_ctx, dim3(B),       dim3(256), 0, stream, features, wv, c0, enc_mean, ctxb);
  hipLaunchKernelGGL(k_base1,    dim3(B),       dim3(256), 0, stream, enc_mean, W1, b1, base1);

  // x1 = base1 + emb @ W1decᵀ  (MFMA)
  hipLaunchKernelGGL(k_gather_emb, dim3(2048),  dim3(256), 0, stream, embed_W, captions, Xe);
  hipLaunchKernelGGL(k_cvt_w1d,    dim3(512),   dim3(256), 0, stream, W1, w1db);
  hipLaunchKernelGGL(k_x1_mfma,    dim3(8, 32), dim3(256), 0, stream, Xe, w1db, base1, xA);

  // conv layer 1
  hipLaunchKernelGGL(k_cvt_wconv, dim3(1024),   dim3(256), 0, stream, cw1, wbuf);
  hipLaunchKernelGGL(k_im2col,    dim3(2048),   dim3(256), 0, stream, xA, Xc);
  hipLaunchKernelGGL(k_conv_mfma, dim3(16, 32), dim3(256), 0, stream, Xc, wbuf, cb1, y);
  hipLaunchKernelGGL(k_glu,       dim3(1024),   dim3(256), 0, stream, y, xA, xB);

  // conv layer 2
  hipLaunchKernelGGL(k_cvt_wconv, dim3(1024),   dim3(256), 0, stream, cw2, wbuf);
  hipLaunchKernelGGL(k_im2col,    dim3(2048),   dim3(256), 0, stream, xB, Xc);
  hipLaunchKernelGGL(k_conv_mfma, dim3(16, 32), dim3(256), 0, stream, Xc, wbuf, cb2, y);
  hipLaunchKernelGGL(k_glu_bf16,  dim3(1024),   dim3(256), 0, stream, y, xB, x3b);

  hipLaunchKernelGGL(k_cbase_mfma, dim3(235),   dim3(256), 0, stream, ctxb, W2, b2, cbase);
  hipLaunchKernelGGL(k_logits_mfma, dim3(235, 16), dim3(256), 0, stream, x3b, W2d, cbase, out);
}